// Round 5
// baseline (681.974 us; speedup 1.0000x reference)
//
#include <hip/hip_runtime.h>

typedef short bf16x8 __attribute__((ext_vector_type(8)));
typedef float floatx4 __attribute__((ext_vector_type(4)));

#define MFMA16(a, b, c) __builtin_amdgcn_mfma_f32_16x16x32_bf16((a), (b), (c), 0, 0, 0)

__device__ __forceinline__ unsigned short f2bf(float f) {
    union { float f; unsigned int u; } v; v.f = f;
    unsigned int u = v.u;
    return (unsigned short)((u + 0x7FFFu + ((u >> 16) & 1u)) >> 16);
}

// async global->LDS, 16B per lane; lds base must be wave-uniform (m97 pattern)
__device__ __forceinline__ void gld_lds16(const void* g, void* l) {
    __builtin_amdgcn_global_load_lds(
        (const __attribute__((address_space(1))) unsigned int*)g,
        (__attribute__((address_space(3))) unsigned int*)l, 16, 0, 0);
}

// ---------------------------------------------------------------- LayerNorm
__global__ __launch_bounds__(256) void ln_kernel(
        const float* __restrict__ x, const float* __restrict__ g,
        const float* __restrict__ be, float* __restrict__ yo,
        unsigned short* __restrict__ yb) {
    int row = blockIdx.x, t = threadIdx.x;
    const float* xr = x + (size_t)row * 2048;
    float4 a = ((const float4*)xr)[2 * t];
    float4 b = ((const float4*)xr)[2 * t + 1];
    float s = a.x + a.y + a.z + a.w + b.x + b.y + b.z + b.w;
    float q = a.x * a.x + a.y * a.y + a.z * a.z + a.w * a.w +
              b.x * b.x + b.y * b.y + b.z * b.z + b.w * b.w;
    for (int m = 1; m < 64; m <<= 1) { s += __shfl_xor(s, m); q += __shfl_xor(q, m); }
    __shared__ float red[8];
    if ((t & 63) == 0) { red[t >> 6] = s; red[4 + (t >> 6)] = q; }
    __syncthreads();
    s = red[0] + red[1] + red[2] + red[3];
    q = red[4] + red[5] + red[6] + red[7];
    float mean = s * (1.0f / 2048.0f);
    float var = q * (1.0f / 2048.0f) - mean * mean;
    float rs = rsqrtf(var + 1e-12f);
    float4 g0 = ((const float4*)g)[2 * t], g1 = ((const float4*)g)[2 * t + 1];
    float4 b0 = ((const float4*)be)[2 * t], b1 = ((const float4*)be)[2 * t + 1];
    float4 y0, y1;
    y0.x = (a.x - mean) * rs * g0.x + b0.x;
    y0.y = (a.y - mean) * rs * g0.y + b0.y;
    y0.z = (a.z - mean) * rs * g0.z + b0.z;
    y0.w = (a.w - mean) * rs * g0.w + b0.w;
    y1.x = (b.x - mean) * rs * g1.x + b1.x;
    y1.y = (b.y - mean) * rs * g1.y + b1.y;
    y1.z = (b.z - mean) * rs * g1.z + b1.z;
    y1.w = (b.w - mean) * rs * g1.w + b1.w;
    float* yr = yo + (size_t)row * 2048;
    ((float4*)yr)[2 * t] = y0;
    ((float4*)yr)[2 * t + 1] = y1;
    union { unsigned short u[8]; uint4 v; } pk;
    pk.u[0] = f2bf(y0.x); pk.u[1] = f2bf(y0.y); pk.u[2] = f2bf(y0.z); pk.u[3] = f2bf(y0.w);
    pk.u[4] = f2bf(y1.x); pk.u[5] = f2bf(y1.y); pk.u[6] = f2bf(y1.z); pk.u[7] = f2bf(y1.w);
    *(uint4*)(yb + (size_t)row * 2048 + t * 8) = pk.v;
}

// ------------------------------------------- batched transpose fp32 -> bf16
__global__ __launch_bounds__(256) void transpose_cvt(
        const float* __restrict__ src, unsigned short* __restrict__ dst,
        int K, int N) {
    __shared__ unsigned short tile[64][73];
    int n0 = blockIdx.x * 64, k0 = blockIdx.y * 64;
    size_t bo = (size_t)blockIdx.z * K * N;
    int t = threadIdx.x;
    for (int p = 0; p < 4; p++) {
        int idx = p * 256 + t; int r = idx >> 4; int c = (idx & 15) * 4;
        float4 v = *(const float4*)(src + bo + (size_t)(k0 + r) * N + n0 + c);
        tile[r][c] = f2bf(v.x); tile[r][c + 1] = f2bf(v.y);
        tile[r][c + 2] = f2bf(v.z); tile[r][c + 3] = f2bf(v.w);
    }
    __syncthreads();
    for (int p = 0; p < 4; p++) {
        int idx = p * 256 + t; int n = idx >> 4; int c = (idx & 15) * 4;
        ushort4 o;
        o.x = tile[c][n]; o.y = tile[c + 1][n];
        o.z = tile[c + 2][n]; o.w = tile[c + 3][n];
        *(ushort4*)(dst + bo + (size_t)(n0 + n) * K + k0 + c) = o;
    }
}

// ================================================================ QKV GEMM
// 256x256 tile, BK=64, 8 waves (2M x 4N), 8-phase schedule. ALL stages during
// tile t target the NXT buffer only (alias-clean). Uniform vmcnt(4) per phase.
// Best measured variant (164.5 us) — kept as-is this round.
#define NT_QKV 32

__device__ __forceinline__ void stage_A(const unsigned short* __restrict__ Ag,
        unsigned short* As, int mh, int m0, int kt, int tid) {
#pragma unroll
    for (int j = 0; j < 2; j++) {
        int G = j * 512 + tid;
        int s = (G >> 3) & 63;
        int gr = G & 7;
        int row = j * 128 + mh * 64 + s;
        const unsigned short* src =
            Ag + (size_t)(m0 + row) * 2048 + kt * 64 + ((gr ^ (s & 7)) << 3);
        unsigned short* dst = As + j * 8192 + mh * 4096 + (tid >> 6) * 512;
        gld_lds16(src, dst);
    }
}

__device__ __forceinline__ void stage_B(const unsigned short* __restrict__ Bg,
        unsigned short* Bs, int nh, int n0, int kt, int tid) {
#pragma unroll
    for (int j = 0; j < 2; j++) {
        int G = j * 512 + tid;
        int wcc = G >> 8;
        int s = (G >> 3) & 31;
        int gr = G & 7;
        int row = wcc * 64 + nh * 32 + s;
        const unsigned short* src =
            Bg + (size_t)(n0 + row) * 2048 + kt * 64 + ((gr ^ (s & 7)) << 3);
        unsigned short* dst = Bs + wcc * 4096 + nh * 2048 + ((tid >> 6) & 3) * 512;
        gld_lds16(src, dst);
    }
}

__device__ __forceinline__ bf16x8 ldfrag(const unsigned short* S, int row, int ks,
                                         int quad, int ln15) {
    int gr = ((ks << 2) | quad) ^ (ln15 & 7);
    return *(const bf16x8*)(S + row * 64 + gr * 8);
}

#define PHASE_SYNC()                                        \
    __builtin_amdgcn_s_barrier();                           \
    asm volatile("s_waitcnt lgkmcnt(0)" ::: "memory");      \
    __builtin_amdgcn_sched_barrier(0);                      \
    __builtin_amdgcn_s_setprio(1)

#define PHASE_END()                                         \
    __builtin_amdgcn_s_setprio(0);                          \
    asm volatile("s_waitcnt vmcnt(4)" ::: "memory");        \
    __builtin_amdgcn_s_barrier()

__device__ __forceinline__ void qkv_tile(
        const unsigned short* __restrict__ Ag, const unsigned short* __restrict__ Bg,
        unsigned short* Asc, unsigned short* Bsc,
        unsigned short* Asn, unsigned short* Bsn,
        int t, int m0, int n0, int tid, int wr, int wc, int ln15, int quad,
        floatx4 (&acc)[8][4]) {
    bf16x8 a[4][2], bb[2][2];
    bool pf = (t + 1 < NT_QKV);
    // ---- phase 0
#pragma unroll
    for (int m = 0; m < 4; m++) {
        a[m][0] = ldfrag(Asc, wr * 128 + m * 16 + ln15, 0, quad, ln15);
        a[m][1] = ldfrag(Asc, wr * 128 + m * 16 + ln15, 1, quad, ln15);
    }
#pragma unroll
    for (int n = 0; n < 2; n++) {
        bb[n][0] = ldfrag(Bsc, wc * 64 + n * 16 + ln15, 0, quad, ln15);
        bb[n][1] = ldfrag(Bsc, wc * 64 + n * 16 + ln15, 1, quad, ln15);
    }
    if (pf) stage_B(Bg, Bsn, 0, n0, t + 1, tid);
    PHASE_SYNC();
#pragma unroll
    for (int m = 0; m < 4; m++)
#pragma unroll
        for (int n = 0; n < 2; n++) {
            acc[m][n] = MFMA16(a[m][0], bb[n][0], acc[m][n]);
            acc[m][n] = MFMA16(a[m][1], bb[n][1], acc[m][n]);
        }
    PHASE_END();
    // ---- phase 1
#pragma unroll
    for (int n = 0; n < 2; n++) {
        bb[n][0] = ldfrag(Bsc, wc * 64 + (2 + n) * 16 + ln15, 0, quad, ln15);
        bb[n][1] = ldfrag(Bsc, wc * 64 + (2 + n) * 16 + ln15, 1, quad, ln15);
    }
    if (pf) stage_A(Ag, Asn, 0, m0, t + 1, tid);
    PHASE_SYNC();
#pragma unroll
    for (int m = 0; m < 4; m++)
#pragma unroll
        for (int n = 0; n < 2; n++) {
            acc[m][2 + n] = MFMA16(a[m][0], bb[n][0], acc[m][2 + n]);
            acc[m][2 + n] = MFMA16(a[m][1], bb[n][1], acc[m][2 + n]);
        }
    PHASE_END();
    // ---- phase 2
#pragma unroll
    for (int m = 0; m < 4; m++) {
        a[m][0] = ldfrag(Asc, wr * 128 + (4 + m) * 16 + ln15, 0, quad, ln15);
        a[m][1] = ldfrag(Asc, wr * 128 + (4 + m) * 16 + ln15, 1, quad, ln15);
    }
    if (pf) stage_B(Bg, Bsn, 1, n0, t + 1, tid);
    PHASE_SYNC();
#pragma unroll
    for (int m = 0; m < 4; m++)
#pragma unroll
        for (int n = 0; n < 2; n++) {
            acc[4 + m][2 + n] = MFMA16(a[m][0], bb[n][0], acc[4 + m][2 + n]);
            acc[4 + m][2 + n] = MFMA16(a[m][1], bb[n][1], acc[4 + m][2 + n]);
        }
    PHASE_END();
    // ---- phase 3
#pragma unroll
    for (int n = 0; n < 2; n++) {
        bb[n][0] = ldfrag(Bsc, wc * 64 + n * 16 + ln15, 0, quad, ln15);
        bb[n][1] = ldfrag(Bsc, wc * 64 + n * 16 + ln15, 1, quad, ln15);
    }
    if (pf) stage_A(Ag, Asn, 1, m0, t + 1, tid);
    PHASE_SYNC();
#pragma unroll
    for (int m = 0; m < 4; m++)
#pragma unroll
        for (int n = 0; n < 2; n++) {
            acc[4 + m][n] = MFMA16(a[m][0], bb[n][0], acc[4 + m][n]);
            acc[4 + m][n] = MFMA16(a[m][1], bb[n][1], acc[4 + m][n]);
        }
    PHASE_END();
}

__global__ __launch_bounds__(512, 2) void gemm_qkv(
        const unsigned short* __restrict__ A, const unsigned short* __restrict__ Bt,
        const float* __restrict__ bias, float* __restrict__ ko,
        float* __restrict__ vo, unsigned short* __restrict__ qws,
        unsigned short* __restrict__ kbf) {
    __shared__ __align__(16) unsigned short As[2][16384];
    __shared__ __align__(16) unsigned short Bs[2][16384];
    int bid = blockIdx.x;
    int xcd = bid & 7, idx = bid >> 3;
    int mt = (xcd & 3) * 4 + idx / 12;
    int ntile = (xcd >> 2) * 12 + idx % 12;
    int m0 = mt * 256, n0 = ntile * 256;
    int tid = threadIdx.x;
    int wave = tid >> 6, lane = tid & 63, ln15 = lane & 15, quad = lane >> 4;
    int wr = wave >> 2, wc = wave & 3;
    floatx4 acc[8][4] = {};
    stage_B(Bt, Bs[0], 0, n0, 0, tid);
    stage_A(A, As[0], 0, m0, 0, tid);
    stage_B(Bt, Bs[0], 1, n0, 0, tid);
    stage_A(A, As[0], 1, m0, 0, tid);
    asm volatile("s_waitcnt vmcnt(4)" ::: "memory");
    __builtin_amdgcn_s_barrier();
#pragma unroll 1
    for (int t = 0; t < NT_QKV; t += 2) {
        qkv_tile(A, Bt, As[0], Bs[0], As[1], Bs[1], t,     m0, n0, tid, wr, wc, ln15, quad, acc);
        qkv_tile(A, Bt, As[1], Bs[1], As[0], Bs[0], t + 1, m0, n0, tid, wr, wc, ln15, quad, acc);
    }
#pragma unroll
    for (int mi = 0; mi < 8; mi++) {
        int row = m0 + wr * 128 + mi * 16 + quad * 4;
#pragma unroll
        for (int ni = 0; ni < 4; ni++) {
            int col = n0 + wc * 64 + ni * 16 + ln15;
            float bv = bias[col];
#pragma unroll
            for (int r = 0; r < 4; r++) {
                float val = acc[mi][ni][r] + bv;
                int rr = row + r;
                int b = rr >> 11, s = rr & 2047;
                if (col < 2048) {
                    qws[(size_t)rr * 2048 + col] = f2bf(val);
                } else if (col < 4096) {
                    int cc = col - 2048; int h = cc >> 7, d = cc & 127;
                    size_t o = ((size_t)(b * 16 + h) * 2048 + s) * 128 + d;
                    ko[o] = val;
                    kbf[o] = f2bf(val);
                } else {
                    int cc = col - 4096; int h = cc >> 7, d = cc & 127;
                    vo[((size_t)(b * 16 + h) * 2048 + s) * 128 + d] = val;
                }
            }
        }
    }
}

// ------------------------------------------------------------- output GEMM
__global__ __launch_bounds__(256) void gemm_out(
        const float* __restrict__ Actx, const unsigned short* __restrict__ Bt,
        float* __restrict__ out) {
    __shared__ unsigned short As[128 * 72];
    __shared__ unsigned short Bs[128 * 72];
    int m0 = blockIdx.y * 128, n0 = blockIdx.x * 128;
    int t = threadIdx.x;
    int wave = t >> 6, lane = t & 63, ln15 = lane & 15, quad = lane >> 4;
    int wm = wave >> 1, wn = wave & 1;
    floatx4 acc[4][4] = {};
    for (int k0 = 0; k0 < 2048; k0 += 64) {
        for (int p = 0; p < 4; p++) {
            int idx = p * 256 + t; int r = idx >> 3; int c = (idx & 7) * 8;
            const float* ap = Actx + (size_t)(m0 + r) * 2048 + k0 + c;
            float4 u0 = ((const float4*)ap)[0], u1 = ((const float4*)ap)[1];
            union { unsigned short u[8]; uint4 v; } pk;
            pk.u[0] = f2bf(u0.x); pk.u[1] = f2bf(u0.y); pk.u[2] = f2bf(u0.z); pk.u[3] = f2bf(u0.w);
            pk.u[4] = f2bf(u1.x); pk.u[5] = f2bf(u1.y); pk.u[6] = f2bf(u1.z); pk.u[7] = f2bf(u1.w);
            *(uint4*)&As[r * 72 + c] = pk.v;
            *(uint4*)&Bs[r * 72 + c] = *(const uint4*)(Bt + (size_t)(n0 + r) * 2048 + k0 + c);
        }
        __syncthreads();
        for (int ks = 0; ks < 2; ks++) {
            bf16x8 af[4], bfr[4];
            for (int i = 0; i < 4; i++)
                af[i] = *(const bf16x8*)&As[(wm * 64 + i * 16 + ln15) * 72 + ks * 32 + quad * 8];
            for (int i = 0; i < 4; i++)
                bfr[i] = *(const bf16x8*)&Bs[(wn * 64 + i * 16 + ln15) * 72 + ks * 32 + quad * 8];
            for (int mi = 0; mi < 4; mi++)
                for (int ni = 0; ni < 4; ni++)
                    acc[mi][ni] = MFMA16(af[mi], bfr[ni], acc[mi][ni]);
        }
        __syncthreads();
    }
    for (int mi = 0; mi < 4; mi++) {
        int row = m0 + wm * 64 + mi * 16 + quad * 4;
        for (int ni = 0; ni < 4; ni++) {
            int col = n0 + wn * 64 + ni * 16 + ln15;
            for (int r = 0; r < 4; r++)
                out[(size_t)(row + r) * 2048 + col] = acc[mi][ni][r];
        }
    }
}

// ---------------------------------------------------------- flash attention
// Q-tile 128/block (4 waves x 32 q-rows as 2 groups of 16); K/V tile 64.
// T14 async-stage (regs -> LDS write-late), T13 defer-max, T5 setprio.
// grid (16, HEADS, B); j = 15 - blockIdx.x so heavy blocks launch first.
__device__ __forceinline__ void load_kv(const unsigned short* __restrict__ kb,
                                        const unsigned short* __restrict__ vTb,
                                        int c0, int t, uint4 (&kg)[4], uint4 (&vg)[4]) {
#pragma unroll
    for (int p = 0; p < 4; p++) {
        int idx = p * 256 + t;
        int r = idx >> 4, c = (idx & 15) * 8;
        kg[p] = *(const uint4*)(kb + (size_t)(c0 + r) * 128 + c);
        int d = idx >> 3, sg = (idx & 7) * 8;
        vg[p] = *(const uint4*)(vTb + (size_t)d * 2048 + c0 + sg);
    }
}

__global__ __launch_bounds__(256, 2) void attn_kernel(
        const unsigned short* __restrict__ qws, const unsigned short* __restrict__ kbf,
        const unsigned short* __restrict__ vT, const float* __restrict__ mask,
        float* __restrict__ ctxo) {
    __shared__ unsigned short Ks[64 * 136];
    __shared__ unsigned short Vt[128 * 72];
    __shared__ unsigned short Pl[4 * 32 * 72];
    int j = 15 - (int)blockIdx.x, h = blockIdx.y, b = blockIdx.z;
    int t = threadIdx.x, wave = t >> 6, lane = t & 63, ln15 = lane & 15, quad = lane >> 4;
    const float scale = 0.08838834764831845f;  // 1/sqrt(128)

    const unsigned short* kb = kbf + (size_t)(b * 16 + h) * 2048 * 128;
    const unsigned short* vTb = vT + (size_t)(b * 16 + h) * 128 * 2048;
    const float* mb = mask + (size_t)b * 2048;
    int Q0 = j * 128;

    // Q fragments: wave rows Q0 + wave*32 + g*16 + ln15
    bf16x8 qf[2][4];
#pragma unroll
    for (int g = 0; g < 2; g++) {
        const unsigned short* qbase =
            qws + ((size_t)(b * 2048 + Q0 + wave * 32 + g * 16 + ln15)) * 2048 + h * 128;
#pragma unroll
        for (int ks = 0; ks < 4; ks++)
            qf[g][ks] = *(const bf16x8*)(qbase + ks * 32 + quad * 8);
    }

    float m_r[2][4], l_r[2][4];
    floatx4 o[2][8] = {};
#pragma unroll
    for (int g = 0; g < 2; g++)
#pragma unroll
        for (int r = 0; r < 4; r++) { m_r[g][r] = -1e30f; l_r[g][r] = 0.0f; }

    int nkt = 2 * j + 2;
    uint4 kg[4], vg[4];
    load_kv(kb, vTb, 0, t, kg, vg);  // prefetch tile 0

#pragma unroll 1
    for (int kt = 0; kt < nkt; kt++) {
        int c0 = kt * 64;
        __syncthreads();  // prior iteration's LDS reads complete
#pragma unroll
        for (int p = 0; p < 4; p++) {
            int idx = p * 256 + t;
            int r = idx >> 4, c = (idx & 15) * 8;
            *(uint4*)&Ks[r * 136 + c] = kg[p];
            int d = idx >> 3, sg = (idx & 7) * 8;
            *(uint4*)&Vt[d * 72 + sg] = vg[p];
        }
        __syncthreads();
        if (kt + 1 < nkt) load_kv(kb, vTb, c0 + 64, t, kg, vg);  // lands under compute

        // S = Q @ K^T : cs[g][ni], K-frags shared across both q-groups
        floatx4 cs[2][4] = {};
        __builtin_amdgcn_s_setprio(1);
#pragma unroll
        for (int ks = 0; ks < 4; ks++) {
            bf16x8 k0 = *(const bf16x8*)&Ks[(0 * 16 + ln15) * 136 + ks * 32 + quad * 8];
            bf16x8 k1 = *(const bf16x8*)&Ks[(1 * 16 + ln15) * 136 + ks * 32 + quad * 8];
            bf16x8 k2 = *(const bf16x8*)&Ks[(2 * 16 + ln15) * 136 + ks * 32 + quad * 8];
            bf16x8 k3 = *(const bf16x8*)&Ks[(3 * 16 + ln15) * 136 + ks * 32 + quad * 8];
#pragma unroll
            for (int g = 0; g < 2; g++) {
                cs[g][0] = MFMA16(qf[g][ks], k0, cs[g][0]);
                cs[g][1] = MFMA16(qf[g][ks], k1, cs[g][1]);
                cs[g][2] = MFMA16(qf[g][ks], k2, cs[g][2]);
                cs[g][3] = MFMA16(qf[g][ks], k3, cs[g][3]);
            }
        }
        __builtin_amdgcn_s_setprio(0);

        // scale + mask + row max
        float mt[2][4];
#pragma unroll
        for (int g = 0; g < 2; g++) {
#pragma unroll
            for (int r = 0; r < 4; r++) mt[g][r] = -1e30f;
#pragma unroll
            for (int ni = 0; ni < 4; ni++) {
                int cg = c0 + ni * 16 + ln15;
                float mk = mb[cg];
#pragma unroll
                for (int r = 0; r < 4; r++) {
                    int qg = Q0 + wave * 32 + g * 16 + quad * 4 + r;
                    float v = fmaf(cs[g][ni][r], scale, mk);
                    v = (cg <= qg) ? v : -10000.0f;
                    cs[g][ni][r] = v;
                    mt[g][r] = fmaxf(mt[g][r], v);
                }
            }
#pragma unroll
            for (int m = 1; m < 16; m <<= 1)
#pragma unroll
                for (int r = 0; r < 4; r++)
                    mt[g][r] = fmaxf(mt[g][r], __shfl_xor(mt[g][r], m));
        }

        // T13 defer-max: rescale only if a row max grew past threshold
        bool grow = false;
#pragma unroll
        for (int g = 0; g < 2; g++)
#pragma unroll
            for (int r = 0; r < 4; r++)
                grow = grow || (mt[g][r] > m_r[g][r] + 8.0f);
        if (__any((int)grow)) {
#pragma unroll
            for (int g = 0; g < 2; g++)
#pragma unroll
                for (int r = 0; r < 4; r++) {
                    float mn = fmaxf(m_r[g][r], mt[g][r]);
                    float alpha = __expf(m_r[g][r] - mn);
                    m_r[g][r] = mn;
                    l_r[g][r] *= alpha;
#pragma unroll
                    for (int nj = 0; nj < 8; nj++) o[g][nj][r] *= alpha;
                }
        }

        // P = exp(s - m), row sums, write P to LDS (wave-private region)
#pragma unroll
        for (int g = 0; g < 2; g++) {
            float lt[4] = {0.0f, 0.0f, 0.0f, 0.0f};
#pragma unroll
            for (int ni = 0; ni < 4; ni++)
#pragma unroll
                for (int r = 0; r < 4; r++) {
                    float p = __expf(cs[g][ni][r] - m_r[g][r]);
                    cs[g][ni][r] = p;
                    lt[r] += p;
                }
#pragma unroll
            for (int m = 1; m < 16; m <<= 1)
#pragma unroll
                for (int r = 0; r < 4; r++) lt[r] += __shfl_xor(lt[r], m);
#pragma unroll
            for (int r = 0; r < 4; r++) l_r[g][r] += lt[r];
            unsigned short* pw = &Pl[(wave * 32 + g * 16) * 72];
#pragma unroll
            for (int ni = 0; ni < 4; ni++)
#pragma unroll
                for (int r = 0; r < 4; r++)
                    pw[(quad * 4 + r) * 72 + ni * 16 + ln15] = f2bf(cs[g][ni][r]);
        }

        // O += P @ V : V-frags shared across both q-groups
        __builtin_amdgcn_s_setprio(1);
#pragma unroll
        for (int ks2 = 0; ks2 < 2; ks2++) {
            bf16x8 pf0 = *(const bf16x8*)&Pl[(wave * 32 + 0 * 16 + ln15) * 72 + ks2 * 32 + quad * 8];
            bf16x8 pf1 = *(const bf16x8*)&Pl[(wave * 32 + 1 * 16 + ln15) * 72 + ks2 * 32 + quad * 8];
#pragma unroll
            for (int nj = 0; nj < 8; nj++) {
                bf16x8 vf = *(const bf16x8*)&Vt[(nj * 16 + ln15) * 72 + ks2 * 32 + quad * 8];
                o[0][nj] = MFMA16(pf0, vf, o[0][nj]);
                o[1][nj] = MFMA16(pf1, vf, o[1][nj]);
            }
        }
        __builtin_amdgcn_s_setprio(0);
    }

    // epilogue
#pragma unroll
    for (int g = 0; g < 2; g++) {
        float rl[4];
#pragma unroll
        for (int r = 0; r < 4; r++) rl[r] = 1.0f / l_r[g][r];
#pragma unroll
        for (int nj = 0; nj < 8; nj++)
#pragma unroll
            for (int r = 0; r < 4; r++) {
                int s = Q0 + wave * 32 + g * 16 + quad * 4 + r;
                ctxo[((size_t)(b * 2048 + s)) * 2048 + h * 128 + nj * 16 + ln15] =
                    o[g][nj][r] * rl[r];
            }
    }
}

extern "C" void kernel_launch(void* const* d_in, const int* in_sizes, int n_in,
                              void* d_out, int out_size, void* d_ws, size_t ws_size,
                              hipStream_t stream) {
    const float* x      = (const float*)d_in[0];
    const float* mask   = (const float*)d_in[1];
    const float* qkvw   = (const float*)d_in[2];
    const float* qkvb   = (const float*)d_in[3];
    const float* ow     = (const float*)d_in[4];
    const float* norm_w = (const float*)d_in[5];
    const float* norm_b = (const float*)d_in[6];

    float* out      = (float*)d_out;             // [B,S,H]
    float* k_out    = out + 8388608;             // [B,Hd,S,dh]
    float* v_out    = out + 16777216;            // [B,Hd,S,dh]
    float* ctx_out  = out + 25165824;            // [B,S,H]
    float* norm_out = out + 33554432;            // [B,S,H]

    unsigned short* ws    = (unsigned short*)d_ws;
    unsigned short* xn    = ws;                        // 8,388,608  bf16
    unsigned short* qkvwT = ws + 8388608;              // 12,582,912 bf16 [6144][2048]
    unsigned short* owT   = ws + 8388608 + 12582912;   // 4,194,304  bf16 [2048][2048]
    unsigned short* qws   = owT + 4194304;             // 8,388,608  bf16 [B*S][H]
    unsigned short* vT    = qws + 8388608;             // 8,388,608  bf16 [B*Hd][dh][S]
    unsigned short* kbf   = vT + 8388608;              // 8,388,608  bf16 [B*Hd][S][dh]

    ln_kernel<<<4096, 256, 0, stream>>>(x, norm_w, norm_b, norm_out, xn);
    transpose_cvt<<<dim3(96, 32, 1), 256, 0, stream>>>(qkvw, qkvwT, 2048, 6144);
    transpose_cvt<<<dim3(32, 32, 1), 256, 0, stream>>>(ow, owT, 2048, 2048);
    gemm_qkv<<<dim3(384), 512, 0, stream>>>(xn, qkvwT, qkvb, k_out, v_out, qws, kbf);
    transpose_cvt<<<dim3(2, 32, 32), 256, 0, stream>>>(v_out, vT, 2048, 128);
    attn_kernel<<<dim3(16, 16, 2), 256, 0, stream>>>(qws, kbf, vT, mask, ctx_out);
    gemm_out<<<dim3(16, 32), 256, 0, stream>>>(ctx_out, owT, out);
}

// Round 6
// 650.333 us; speedup vs baseline: 1.0487x; 1.0487x over previous
//
#include <hip/hip_runtime.h>

typedef short bf16x8 __attribute__((ext_vector_type(8)));
typedef float floatx4 __attribute__((ext_vector_type(4)));

#define MFMA16(a, b, c) __builtin_amdgcn_mfma_f32_16x16x32_bf16((a), (b), (c), 0, 0, 0)

__device__ __forceinline__ unsigned short f2bf(float f) {
    union { float f; unsigned int u; } v; v.f = f;
    unsigned int u = v.u;
    return (unsigned short)((u + 0x7FFFu + ((u >> 16) & 1u)) >> 16);
}

// async global->LDS, 16B per lane; lds base must be wave-uniform (m97 pattern)
__device__ __forceinline__ void gld_lds16(const void* g, void* l) {
    __builtin_amdgcn_global_load_lds(
        (const __attribute__((address_space(1))) unsigned int*)g,
        (__attribute__((address_space(3))) unsigned int*)l, 16, 0, 0);
}

// ---------------------------------------------------------------- LayerNorm
__global__ __launch_bounds__(256) void ln_kernel(
        const float* __restrict__ x, const float* __restrict__ g,
        const float* __restrict__ be, float* __restrict__ yo,
        unsigned short* __restrict__ yb) {
    int row = blockIdx.x, t = threadIdx.x;
    const float* xr = x + (size_t)row * 2048;
    float4 a = ((const float4*)xr)[2 * t];
    float4 b = ((const float4*)xr)[2 * t + 1];
    float s = a.x + a.y + a.z + a.w + b.x + b.y + b.z + b.w;
    float q = a.x * a.x + a.y * a.y + a.z * a.z + a.w * a.w +
              b.x * b.x + b.y * b.y + b.z * b.z + b.w * b.w;
    for (int m = 1; m < 64; m <<= 1) { s += __shfl_xor(s, m); q += __shfl_xor(q, m); }
    __shared__ float red[8];
    if ((t & 63) == 0) { red[t >> 6] = s; red[4 + (t >> 6)] = q; }
    __syncthreads();
    s = red[0] + red[1] + red[2] + red[3];
    q = red[4] + red[5] + red[6] + red[7];
    float mean = s * (1.0f / 2048.0f);
    float var = q * (1.0f / 2048.0f) - mean * mean;
    float rs = rsqrtf(var + 1e-12f);
    float4 g0 = ((const float4*)g)[2 * t], g1 = ((const float4*)g)[2 * t + 1];
    float4 b0 = ((const float4*)be)[2 * t], b1 = ((const float4*)be)[2 * t + 1];
    float4 y0, y1;
    y0.x = (a.x - mean) * rs * g0.x + b0.x;
    y0.y = (a.y - mean) * rs * g0.y + b0.y;
    y0.z = (a.z - mean) * rs * g0.z + b0.z;
    y0.w = (a.w - mean) * rs * g0.w + b0.w;
    y1.x = (b.x - mean) * rs * g1.x + b1.x;
    y1.y = (b.y - mean) * rs * g1.y + b1.y;
    y1.z = (b.z - mean) * rs * g1.z + b1.z;
    y1.w = (b.w - mean) * rs * g1.w + b1.w;
    float* yr = yo + (size_t)row * 2048;
    ((float4*)yr)[2 * t] = y0;
    ((float4*)yr)[2 * t + 1] = y1;
    union { unsigned short u[8]; uint4 v; } pk;
    pk.u[0] = f2bf(y0.x); pk.u[1] = f2bf(y0.y); pk.u[2] = f2bf(y0.z); pk.u[3] = f2bf(y0.w);
    pk.u[4] = f2bf(y1.x); pk.u[5] = f2bf(y1.y); pk.u[6] = f2bf(y1.z); pk.u[7] = f2bf(y1.w);
    *(uint4*)(yb + (size_t)row * 2048 + t * 8) = pk.v;
}

// ------------------------------------------- batched transpose fp32 -> bf16
__global__ __launch_bounds__(256) void transpose_cvt(
        const float* __restrict__ src, unsigned short* __restrict__ dst,
        int K, int N) {
    __shared__ unsigned short tile[64][73];
    int n0 = blockIdx.x * 64, k0 = blockIdx.y * 64;
    size_t bo = (size_t)blockIdx.z * K * N;
    int t = threadIdx.x;
    for (int p = 0; p < 4; p++) {
        int idx = p * 256 + t; int r = idx >> 4; int c = (idx & 15) * 4;
        float4 v = *(const float4*)(src + bo + (size_t)(k0 + r) * N + n0 + c);
        tile[r][c] = f2bf(v.x); tile[r][c + 1] = f2bf(v.y);
        tile[r][c + 2] = f2bf(v.z); tile[r][c + 3] = f2bf(v.w);
    }
    __syncthreads();
    for (int p = 0; p < 4; p++) {
        int idx = p * 256 + t; int n = idx >> 4; int c = (idx & 15) * 4;
        ushort4 o;
        o.x = tile[c][n]; o.y = tile[c + 1][n];
        o.z = tile[c + 2][n]; o.w = tile[c + 3][n];
        *(ushort4*)(dst + bo + (size_t)(n0 + n) * K + k0 + c) = o;
    }
}

// ================================================================ QKV GEMM
// 256x256 tile, BK=64, 8 waves (2M x 4N), 8-phase schedule. ALL stages during
// tile t target the NXT buffer only (alias-clean). Uniform vmcnt(4) per phase.
// Best measured variant (164.5 us) — kept as-is.
#define NT_QKV 32

__device__ __forceinline__ void stage_A(const unsigned short* __restrict__ Ag,
        unsigned short* As, int mh, int m0, int kt, int tid) {
#pragma unroll
    for (int j = 0; j < 2; j++) {
        int G = j * 512 + tid;
        int s = (G >> 3) & 63;
        int gr = G & 7;
        int row = j * 128 + mh * 64 + s;
        const unsigned short* src =
            Ag + (size_t)(m0 + row) * 2048 + kt * 64 + ((gr ^ (s & 7)) << 3);
        unsigned short* dst = As + j * 8192 + mh * 4096 + (tid >> 6) * 512;
        gld_lds16(src, dst);
    }
}

__device__ __forceinline__ void stage_B(const unsigned short* __restrict__ Bg,
        unsigned short* Bs, int nh, int n0, int kt, int tid) {
#pragma unroll
    for (int j = 0; j < 2; j++) {
        int G = j * 512 + tid;
        int wcc = G >> 8;
        int s = (G >> 3) & 31;
        int gr = G & 7;
        int row = wcc * 64 + nh * 32 + s;
        const unsigned short* src =
            Bg + (size_t)(n0 + row) * 2048 + kt * 64 + ((gr ^ (s & 7)) << 3);
        unsigned short* dst = Bs + wcc * 4096 + nh * 2048 + ((tid >> 6) & 3) * 512;
        gld_lds16(src, dst);
    }
}

__device__ __forceinline__ bf16x8 ldfrag(const unsigned short* S, int row, int ks,
                                         int quad, int ln15) {
    int gr = ((ks << 2) | quad) ^ (ln15 & 7);
    return *(const bf16x8*)(S + row * 64 + gr * 8);
}

#define PHASE_SYNC()                                        \
    __builtin_amdgcn_s_barrier();                           \
    asm volatile("s_waitcnt lgkmcnt(0)" ::: "memory");      \
    __builtin_amdgcn_sched_barrier(0);                      \
    __builtin_amdgcn_s_setprio(1)

#define PHASE_END()                                         \
    __builtin_amdgcn_s_setprio(0);                          \
    asm volatile("s_waitcnt vmcnt(4)" ::: "memory");        \
    __builtin_amdgcn_s_barrier()

__device__ __forceinline__ void qkv_tile(
        const unsigned short* __restrict__ Ag, const unsigned short* __restrict__ Bg,
        unsigned short* Asc, unsigned short* Bsc,
        unsigned short* Asn, unsigned short* Bsn,
        int t, int m0, int n0, int tid, int wr, int wc, int ln15, int quad,
        floatx4 (&acc)[8][4]) {
    bf16x8 a[4][2], bb[2][2];
    bool pf = (t + 1 < NT_QKV);
    // ---- phase 0
#pragma unroll
    for (int m = 0; m < 4; m++) {
        a[m][0] = ldfrag(Asc, wr * 128 + m * 16 + ln15, 0, quad, ln15);
        a[m][1] = ldfrag(Asc, wr * 128 + m * 16 + ln15, 1, quad, ln15);
    }
#pragma unroll
    for (int n = 0; n < 2; n++) {
        bb[n][0] = ldfrag(Bsc, wc * 64 + n * 16 + ln15, 0, quad, ln15);
        bb[n][1] = ldfrag(Bsc, wc * 64 + n * 16 + ln15, 1, quad, ln15);
    }
    if (pf) stage_B(Bg, Bsn, 0, n0, t + 1, tid);
    PHASE_SYNC();
#pragma unroll
    for (int m = 0; m < 4; m++)
#pragma unroll
        for (int n = 0; n < 2; n++) {
            acc[m][n] = MFMA16(a[m][0], bb[n][0], acc[m][n]);
            acc[m][n] = MFMA16(a[m][1], bb[n][1], acc[m][n]);
        }
    PHASE_END();
    // ---- phase 1
#pragma unroll
    for (int n = 0; n < 2; n++) {
        bb[n][0] = ldfrag(Bsc, wc * 64 + (2 + n) * 16 + ln15, 0, quad, ln15);
        bb[n][1] = ldfrag(Bsc, wc * 64 + (2 + n) * 16 + ln15, 1, quad, ln15);
    }
    if (pf) stage_A(Ag, Asn, 0, m0, t + 1, tid);
    PHASE_SYNC();
#pragma unroll
    for (int m = 0; m < 4; m++)
#pragma unroll
        for (int n = 0; n < 2; n++) {
            acc[m][2 + n] = MFMA16(a[m][0], bb[n][0], acc[m][2 + n]);
            acc[m][2 + n] = MFMA16(a[m][1], bb[n][1], acc[m][2 + n]);
        }
    PHASE_END();
    // ---- phase 2
#pragma unroll
    for (int m = 0; m < 4; m++) {
        a[m][0] = ldfrag(Asc, wr * 128 + (4 + m) * 16 + ln15, 0, quad, ln15);
        a[m][1] = ldfrag(Asc, wr * 128 + (4 + m) * 16 + ln15, 1, quad, ln15);
    }
    if (pf) stage_B(Bg, Bsn, 1, n0, t + 1, tid);
    PHASE_SYNC();
#pragma unroll
    for (int m = 0; m < 4; m++)
#pragma unroll
        for (int n = 0; n < 2; n++) {
            acc[4 + m][2 + n] = MFMA16(a[m][0], bb[n][0], acc[4 + m][2 + n]);
            acc[4 + m][2 + n] = MFMA16(a[m][1], bb[n][1], acc[4 + m][2 + n]);
        }
    PHASE_END();
    // ---- phase 3
#pragma unroll
    for (int n = 0; n < 2; n++) {
        bb[n][0] = ldfrag(Bsc, wc * 64 + n * 16 + ln15, 0, quad, ln15);
        bb[n][1] = ldfrag(Bsc, wc * 64 + n * 16 + ln15, 1, quad, ln15);
    }
    if (pf) stage_A(Ag, Asn, 1, m0, t + 1, tid);
    PHASE_SYNC();
#pragma unroll
    for (int m = 0; m < 4; m++)
#pragma unroll
        for (int n = 0; n < 2; n++) {
            acc[4 + m][n] = MFMA16(a[m][0], bb[n][0], acc[4 + m][n]);
            acc[4 + m][n] = MFMA16(a[m][1], bb[n][1], acc[4 + m][n]);
        }
    PHASE_END();
}

__global__ __launch_bounds__(512, 2) void gemm_qkv(
        const unsigned short* __restrict__ A, const unsigned short* __restrict__ Bt,
        const float* __restrict__ bias, float* __restrict__ ko,
        float* __restrict__ vo, unsigned short* __restrict__ qws,
        unsigned short* __restrict__ kbf) {
    __shared__ __align__(16) unsigned short As[2][16384];
    __shared__ __align__(16) unsigned short Bs[2][16384];
    int bid = blockIdx.x;
    int xcd = bid & 7, idx = bid >> 3;
    int mt = (xcd & 3) * 4 + idx / 12;
    int ntile = (xcd >> 2) * 12 + idx % 12;
    int m0 = mt * 256, n0 = ntile * 256;
    int tid = threadIdx.x;
    int wave = tid >> 6, lane = tid & 63, ln15 = lane & 15, quad = lane >> 4;
    int wr = wave >> 2, wc = wave & 3;
    floatx4 acc[8][4] = {};
    stage_B(Bt, Bs[0], 0, n0, 0, tid);
    stage_A(A, As[0], 0, m0, 0, tid);
    stage_B(Bt, Bs[0], 1, n0, 0, tid);
    stage_A(A, As[0], 1, m0, 0, tid);
    asm volatile("s_waitcnt vmcnt(4)" ::: "memory");
    __builtin_amdgcn_s_barrier();
#pragma unroll 1
    for (int t = 0; t < NT_QKV; t += 2) {
        qkv_tile(A, Bt, As[0], Bs[0], As[1], Bs[1], t,     m0, n0, tid, wr, wc, ln15, quad, acc);
        qkv_tile(A, Bt, As[1], Bs[1], As[0], Bs[0], t + 1, m0, n0, tid, wr, wc, ln15, quad, acc);
    }
#pragma unroll
    for (int mi = 0; mi < 8; mi++) {
        int row = m0 + wr * 128 + mi * 16 + quad * 4;
#pragma unroll
        for (int ni = 0; ni < 4; ni++) {
            int col = n0 + wc * 64 + ni * 16 + ln15;
            float bv = bias[col];
#pragma unroll
            for (int r = 0; r < 4; r++) {
                float val = acc[mi][ni][r] + bv;
                int rr = row + r;
                int b = rr >> 11, s = rr & 2047;
                if (col < 2048) {
                    qws[(size_t)rr * 2048 + col] = f2bf(val);
                } else if (col < 4096) {
                    int cc = col - 2048; int h = cc >> 7, d = cc & 127;
                    size_t o = ((size_t)(b * 16 + h) * 2048 + s) * 128 + d;
                    ko[o] = val;
                    kbf[o] = f2bf(val);
                } else {
                    int cc = col - 4096; int h = cc >> 7, d = cc & 127;
                    vo[((size_t)(b * 16 + h) * 2048 + s) * 128 + d] = val;
                }
            }
        }
    }
}

// ------------------------------------------------------------- output GEMM
__global__ __launch_bounds__(256) void gemm_out(
        const float* __restrict__ Actx, const unsigned short* __restrict__ Bt,
        float* __restrict__ out) {
    __shared__ unsigned short As[128 * 72];
    __shared__ unsigned short Bs[128 * 72];
    int m0 = blockIdx.y * 128, n0 = blockIdx.x * 128;
    int t = threadIdx.x;
    int wave = t >> 6, lane = t & 63, ln15 = lane & 15, quad = lane >> 4;
    int wm = wave >> 1, wn = wave & 1;
    floatx4 acc[4][4] = {};
    for (int k0 = 0; k0 < 2048; k0 += 64) {
        for (int p = 0; p < 4; p++) {
            int idx = p * 256 + t; int r = idx >> 3; int c = (idx & 7) * 8;
            const float* ap = Actx + (size_t)(m0 + r) * 2048 + k0 + c;
            float4 u0 = ((const float4*)ap)[0], u1 = ((const float4*)ap)[1];
            union { unsigned short u[8]; uint4 v; } pk;
            pk.u[0] = f2bf(u0.x); pk.u[1] = f2bf(u0.y); pk.u[2] = f2bf(u0.z); pk.u[3] = f2bf(u0.w);
            pk.u[4] = f2bf(u1.x); pk.u[5] = f2bf(u1.y); pk.u[6] = f2bf(u1.z); pk.u[7] = f2bf(u1.w);
            *(uint4*)&As[r * 72 + c] = pk.v;
            *(uint4*)&Bs[r * 72 + c] = *(const uint4*)(Bt + (size_t)(n0 + r) * 2048 + k0 + c);
        }
        __syncthreads();
        for (int ks = 0; ks < 2; ks++) {
            bf16x8 af[4], bfr[4];
            for (int i = 0; i < 4; i++)
                af[i] = *(const bf16x8*)&As[(wm * 64 + i * 16 + ln15) * 72 + ks * 32 + quad * 8];
            for (int i = 0; i < 4; i++)
                bfr[i] = *(const bf16x8*)&Bs[(wn * 64 + i * 16 + ln15) * 72 + ks * 32 + quad * 8];
            for (int mi = 0; mi < 4; mi++)
                for (int ni = 0; ni < 4; ni++)
                    acc[mi][ni] = MFMA16(af[mi], bfr[ni], acc[mi][ni]);
        }
        __syncthreads();
    }
    for (int mi = 0; mi < 4; mi++) {
        int row = m0 + wm * 64 + mi * 16 + quad * 4;
        for (int ni = 0; ni < 4; ni++) {
            int col = n0 + wn * 64 + ni * 16 + ln15;
            for (int r = 0; r < 4; r++)
                out[(size_t)(row + r) * 2048 + col] = acc[mi][ni][r];
        }
    }
}

// ---------------------------------------------------------- flash attention
// BALANCED structure: grid (16, HEADS, B); block handles q-tile pair
// (jp, 31-jp) -> exactly 33 iterations of 64-q work per block.
// Grafted: T14 async-stage (reg prefetch, LDS write-late, incl. across the
// half boundary), T13 defer-max (THR=8), T5 setprio around MFMA clusters.
__device__ __forceinline__ void load_kv(const unsigned short* __restrict__ kb,
                                        const unsigned short* __restrict__ vTb,
                                        int c0, int t, uint4 (&kg)[4], uint4 (&vg)[4]) {
#pragma unroll
    for (int p = 0; p < 4; p++) {
        int idx = p * 256 + t;
        int r = idx >> 4, c = (idx & 15) * 8;
        kg[p] = *(const uint4*)(kb + (size_t)(c0 + r) * 128 + c);
        int d = idx >> 3, sg = (idx & 7) * 8;
        vg[p] = *(const uint4*)(vTb + (size_t)d * 2048 + c0 + sg);
    }
}

__global__ __launch_bounds__(256, 2) void attn_kernel(
        const unsigned short* __restrict__ qws, const unsigned short* __restrict__ kbf,
        const unsigned short* __restrict__ vT, const float* __restrict__ mask,
        float* __restrict__ ctxo) {
    __shared__ unsigned short Ks[64 * 136];
    __shared__ unsigned short Vt[128 * 72];
    __shared__ unsigned short Pl[4 * 16 * 72];
    int jp = blockIdx.x, h = blockIdx.y, b = blockIdx.z;
    int t = threadIdx.x, wave = t >> 6, lane = t & 63, ln15 = lane & 15, quad = lane >> 4;
    const float scale = 0.08838834764831845f;  // 1/sqrt(128)

    const unsigned short* kb = kbf + (size_t)(b * 16 + h) * 2048 * 128;
    const unsigned short* vTb = vT + (size_t)(b * 16 + h) * 128 * 2048;
    const float* mb = mask + (size_t)b * 2048;

    uint4 kg[4], vg[4];
    load_kv(kb, vTb, 0, t, kg, vg);  // prefetch first tile of half 0

#pragma unroll 1
    for (int half = 0; half < 2; half++) {
        int qt = half ? (31 - jp) : jp;
        int Q0 = qt * 64;

        bf16x8 qf[4];
        const unsigned short* qbase =
            qws + ((size_t)(b * 2048 + Q0 + wave * 16 + ln15)) * 2048 + h * 128;
#pragma unroll
        for (int ks = 0; ks < 4; ks++)
            qf[ks] = *(const bf16x8*)(qbase + ks * 32 + quad * 8);

        float m_r[4], l_r[4];
        floatx4 o[8] = {};
#pragma unroll
        for (int r = 0; r < 4; r++) { m_r[r] = -1e30f; l_r[r] = 0.0f; }

        int nkt = qt + 1;
#pragma unroll 1
        for (int kt = 0; kt < nkt; kt++) {
            int c0 = kt * 64;
            // write staged regs -> LDS (prior iteration's reads done at its
            // trailing barrier; first iteration has no prior reads)
#pragma unroll
            for (int p = 0; p < 4; p++) {
                int idx = p * 256 + t;
                int r = idx >> 4, c = (idx & 15) * 8;
                *(uint4*)&Ks[r * 136 + c] = kg[p];
                int d = idx >> 3, sg = (idx & 7) * 8;
                *(uint4*)&Vt[d * 72 + sg] = vg[p];
            }
            __syncthreads();
            // T14: issue next tile's loads now; they land under compute.
            if (kt + 1 < nkt)      load_kv(kb, vTb, c0 + 64, t, kg, vg);
            else if (half == 0)    load_kv(kb, vTb, 0, t, kg, vg);  // half-1 tile 0

            // S = Q @ K^T  (16 x 64 per wave)
            floatx4 cs[4] = {};
            __builtin_amdgcn_s_setprio(1);
#pragma unroll
            for (int ks = 0; ks < 4; ks++)
#pragma unroll
                for (int ni = 0; ni < 4; ni++) {
                    bf16x8 kfr = *(const bf16x8*)&Ks[(ni * 16 + ln15) * 136 + ks * 32 + quad * 8];
                    cs[ni] = MFMA16(qf[ks], kfr, cs[ni]);
                }
            __builtin_amdgcn_s_setprio(0);

            // scale + mask + row max
            float sv[4][4];
            float mt[4] = {-1e30f, -1e30f, -1e30f, -1e30f};
            if (kt == qt) {
#pragma unroll
                for (int ni = 0; ni < 4; ni++) {
                    int cg = c0 + ni * 16 + ln15;
                    float mk = mb[cg];
#pragma unroll
                    for (int r = 0; r < 4; r++) {
                        int qg = Q0 + wave * 16 + quad * 4 + r;
                        float v = (cg <= qg) ? fmaf(cs[ni][r], scale, mk) : -10000.0f;
                        sv[ni][r] = v;
                        mt[r] = fmaxf(mt[r], v);
                    }
                }
            } else {
#pragma unroll
                for (int ni = 0; ni < 4; ni++) {
                    float mk = mb[c0 + ni * 16 + ln15];
#pragma unroll
                    for (int r = 0; r < 4; r++) {
                        float v = fmaf(cs[ni][r], scale, mk);
                        sv[ni][r] = v;
                        mt[r] = fmaxf(mt[r], v);
                    }
                }
            }
#pragma unroll
            for (int m = 1; m < 16; m <<= 1)
#pragma unroll
                for (int r = 0; r < 4; r++) mt[r] = fmaxf(mt[r], __shfl_xor(mt[r], m));

            // T13 defer-max: only rescale when a row max grows past THR=8
            bool grow = false;
#pragma unroll
            for (int r = 0; r < 4; r++) grow = grow || (mt[r] > m_r[r] + 8.0f);
            if (__any((int)grow)) {
#pragma unroll
                for (int r = 0; r < 4; r++) {
                    float mn = fmaxf(m_r[r], mt[r]);
                    float al = __expf(m_r[r] - mn);
                    m_r[r] = mn;
                    l_r[r] *= al;
#pragma unroll
                    for (int nj = 0; nj < 8; nj++) o[nj][r] *= al;
                }
            }

            // P = exp(s - m), row sums
            float lt[4] = {0.0f, 0.0f, 0.0f, 0.0f};
#pragma unroll
            for (int ni = 0; ni < 4; ni++)
#pragma unroll
                for (int r = 0; r < 4; r++) {
                    float p = __expf(sv[ni][r] - m_r[r]);
                    sv[ni][r] = p;
                    lt[r] += p;
                }
#pragma unroll
            for (int m = 1; m < 16; m <<= 1)
#pragma unroll
                for (int r = 0; r < 4; r++) lt[r] += __shfl_xor(lt[r], m);
#pragma unroll
            for (int r = 0; r < 4; r++) l_r[r] += lt[r];

            // P (C-layout) -> LDS -> A-layout (wave-private region)
            unsigned short* pw = &Pl[wave * 16 * 72];
#pragma unroll
            for (int ni = 0; ni < 4; ni++)
#pragma unroll
                for (int r = 0; r < 4; r++)
                    pw[(quad * 4 + r) * 72 + ni * 16 + ln15] = f2bf(sv[ni][r]);

            // O += P @ V
            __builtin_amdgcn_s_setprio(1);
#pragma unroll
            for (int ks2 = 0; ks2 < 2; ks2++) {
                bf16x8 pf = *(const bf16x8*)&Pl[(wave * 16 + ln15) * 72 + ks2 * 32 + quad * 8];
#pragma unroll
                for (int nj = 0; nj < 8; nj++) {
                    bf16x8 vf = *(const bf16x8*)&Vt[(nj * 16 + ln15) * 72 + ks2 * 32 + quad * 8];
                    o[nj] = MFMA16(pf, vf, o[nj]);
                }
            }
            __builtin_amdgcn_s_setprio(0);
            __syncthreads();
        }

        float rl[4];
#pragma unroll
        for (int r = 0; r < 4; r++) rl[r] = 1.0f / l_r[r];
#pragma unroll
        for (int nj = 0; nj < 8; nj++)
#pragma unroll
            for (int r = 0; r < 4; r++) {
                int s = Q0 + wave * 16 + quad * 4 + r;
                ctxo[((size_t)(b * 2048 + s)) * 2048 + h * 128 + nj * 16 + ln15] = o[nj][r] * rl[r];
            }
    }
}

extern "C" void kernel_launch(void* const* d_in, const int* in_sizes, int n_in,
                              void* d_out, int out_size, void* d_ws, size_t ws_size,
                              hipStream_t stream) {
    const float* x      = (const float*)d_in[0];
    const float* mask   = (const float*)d_in[1];
    const float* qkvw   = (const float*)d_in[2];
    const float* qkvb   = (const float*)d_in[3];
    const float* ow     = (const float*)d_in[4];
    const float* norm_w = (const float*)d_in[5];
    const float* norm_b = (const float*)d_in[6];

    float* out      = (float*)d_out;             // [B,S,H]
    float* k_out    = out + 8388608;             // [B,Hd,S,dh]
    float* v_out    = out + 16777216;            // [B,Hd,S,dh]
    float* ctx_out  = out + 25165824;            // [B,S,H]
    float* norm_out = out + 33554432;            // [B,S,H]

    unsigned short* ws    = (unsigned short*)d_ws;
    unsigned short* xn    = ws;                        // 8,388,608  bf16
    unsigned short* qkvwT = ws + 8388608;              // 12,582,912 bf16 [6144][2048]
    unsigned short* owT   = ws + 8388608 + 12582912;   // 4,194,304  bf16 [2048][2048]
    unsigned short* qws   = owT + 4194304;             // 8,388,608  bf16 [B*S][H]
    unsigned short* vT    = qws + 8388608;             // 8,388,608  bf16 [B*Hd][dh][S]
    unsigned short* kbf   = vT + 8388608;              // 8,388,608  bf16 [B*Hd][S][dh]

    ln_kernel<<<4096, 256, 0, stream>>>(x, norm_w, norm_b, norm_out, xn);
    transpose_cvt<<<dim3(96, 32, 1), 256, 0, stream>>>(qkvw, qkvwT, 2048, 6144);
    transpose_cvt<<<dim3(32, 32, 1), 256, 0, stream>>>(ow, owT, 2048, 2048);
    gemm_qkv<<<dim3(384), 512, 0, stream>>>(xn, qkvwT, qkvb, k_out, v_out, qws, kbf);
    transpose_cvt<<<dim3(2, 32, 32), 256, 0, stream>>>(v_out, vT, 2048, 128);
    attn_kernel<<<dim3(16, 16, 2), 256, 0, stream>>>(qws, kbf, vT, mask, ctx_out);
    gemm_out<<<dim3(16, 32), 256, 0, stream>>>(ctx_out, owT, out);
}

// Round 7
// 550.619 us; speedup vs baseline: 1.2386x; 1.1811x over previous
//
#include <hip/hip_runtime.h>

typedef short bf16x8 __attribute__((ext_vector_type(8)));
typedef float floatx4 __attribute__((ext_vector_type(4)));

#define MFMA16(a, b, c) __builtin_amdgcn_mfma_f32_16x16x32_bf16((a), (b), (c), 0, 0, 0)

__device__ __forceinline__ unsigned short f2bf(float f) {
    union { float f; unsigned int u; } v; v.f = f;
    unsigned int u = v.u;
    return (unsigned short)((u + 0x7FFFu + ((u >> 16) & 1u)) >> 16);
}

// async global->LDS, 16B per lane; lds base must be wave-uniform (m97 pattern)
__device__ __forceinline__ void gld_lds16(const void* g, void* l) {
    __builtin_amdgcn_global_load_lds(
        (const __attribute__((address_space(1))) unsigned int*)g,
        (__attribute__((address_space(3))) unsigned int*)l, 16, 0, 0);
}

// ---------------------------------------------------------------- LayerNorm
__global__ __launch_bounds__(256) void ln_kernel(
        const float* __restrict__ x, const float* __restrict__ g,
        const float* __restrict__ be, float* __restrict__ yo,
        unsigned short* __restrict__ yb) {
    int row = blockIdx.x, t = threadIdx.x;
    const float* xr = x + (size_t)row * 2048;
    float4 a = ((const float4*)xr)[2 * t];
    float4 b = ((const float4*)xr)[2 * t + 1];
    float s = a.x + a.y + a.z + a.w + b.x + b.y + b.z + b.w;
    float q = a.x * a.x + a.y * a.y + a.z * a.z + a.w * a.w +
              b.x * b.x + b.y * b.y + b.z * b.z + b.w * b.w;
    for (int m = 1; m < 64; m <<= 1) { s += __shfl_xor(s, m); q += __shfl_xor(q, m); }
    __shared__ float red[8];
    if ((t & 63) == 0) { red[t >> 6] = s; red[4 + (t >> 6)] = q; }
    __syncthreads();
    s = red[0] + red[1] + red[2] + red[3];
    q = red[4] + red[5] + red[6] + red[7];
    float mean = s * (1.0f / 2048.0f);
    float var = q * (1.0f / 2048.0f) - mean * mean;
    float rs = rsqrtf(var + 1e-12f);
    float4 g0 = ((const float4*)g)[2 * t], g1 = ((const float4*)g)[2 * t + 1];
    float4 b0 = ((const float4*)be)[2 * t], b1 = ((const float4*)be)[2 * t + 1];
    float4 y0, y1;
    y0.x = (a.x - mean) * rs * g0.x + b0.x;
    y0.y = (a.y - mean) * rs * g0.y + b0.y;
    y0.z = (a.z - mean) * rs * g0.z + b0.z;
    y0.w = (a.w - mean) * rs * g0.w + b0.w;
    y1.x = (b.x - mean) * rs * g1.x + b1.x;
    y1.y = (b.y - mean) * rs * g1.y + b1.y;
    y1.z = (b.z - mean) * rs * g1.z + b1.z;
    y1.w = (b.w - mean) * rs * g1.w + b1.w;
    float* yr = yo + (size_t)row * 2048;
    ((float4*)yr)[2 * t] = y0;
    ((float4*)yr)[2 * t + 1] = y1;
    union { unsigned short u[8]; uint4 v; } pk;
    pk.u[0] = f2bf(y0.x); pk.u[1] = f2bf(y0.y); pk.u[2] = f2bf(y0.z); pk.u[3] = f2bf(y0.w);
    pk.u[4] = f2bf(y1.x); pk.u[5] = f2bf(y1.y); pk.u[6] = f2bf(y1.z); pk.u[7] = f2bf(y1.w);
    *(uint4*)(yb + (size_t)row * 2048 + t * 8) = pk.v;
}

// ------------------------------------------- batched transpose fp32 -> bf16
__global__ __launch_bounds__(256) void transpose_cvt(
        const float* __restrict__ src, unsigned short* __restrict__ dst,
        int K, int N) {
    __shared__ unsigned short tile[64][73];
    int n0 = blockIdx.x * 64, k0 = blockIdx.y * 64;
    size_t bo = (size_t)blockIdx.z * K * N;
    int t = threadIdx.x;
    for (int p = 0; p < 4; p++) {
        int idx = p * 256 + t; int r = idx >> 4; int c = (idx & 15) * 4;
        float4 v = *(const float4*)(src + bo + (size_t)(k0 + r) * N + n0 + c);
        tile[r][c] = f2bf(v.x); tile[r][c + 1] = f2bf(v.y);
        tile[r][c + 2] = f2bf(v.z); tile[r][c + 3] = f2bf(v.w);
    }
    __syncthreads();
    for (int p = 0; p < 4; p++) {
        int idx = p * 256 + t; int n = idx >> 4; int c = (idx & 15) * 4;
        ushort4 o;
        o.x = tile[c][n]; o.y = tile[c + 1][n];
        o.z = tile[c + 2][n]; o.w = tile[c + 3][n];
        *(ushort4*)(dst + bo + (size_t)(n0 + n) * K + k0 + c) = o;
    }
}

// ================================================================ QKV GEMM
// 256x256 tile, BK=64, 8 waves (2M x 4N), 8-phase schedule, alias-clean NXT
// staging, uniform vmcnt(4). Best measured variant (164.5 us) — kept as-is.
#define NT_QKV 32

__device__ __forceinline__ void stage_A(const unsigned short* __restrict__ Ag,
        unsigned short* As, int mh, int m0, int kt, int tid) {
#pragma unroll
    for (int j = 0; j < 2; j++) {
        int G = j * 512 + tid;
        int s = (G >> 3) & 63;
        int gr = G & 7;
        int row = j * 128 + mh * 64 + s;
        const unsigned short* src =
            Ag + (size_t)(m0 + row) * 2048 + kt * 64 + ((gr ^ (s & 7)) << 3);
        unsigned short* dst = As + j * 8192 + mh * 4096 + (tid >> 6) * 512;
        gld_lds16(src, dst);
    }
}

__device__ __forceinline__ void stage_B(const unsigned short* __restrict__ Bg,
        unsigned short* Bs, int nh, int n0, int kt, int tid) {
#pragma unroll
    for (int j = 0; j < 2; j++) {
        int G = j * 512 + tid;
        int wcc = G >> 8;
        int s = (G >> 3) & 31;
        int gr = G & 7;
        int row = wcc * 64 + nh * 32 + s;
        const unsigned short* src =
            Bg + (size_t)(n0 + row) * 2048 + kt * 64 + ((gr ^ (s & 7)) << 3);
        unsigned short* dst = Bs + wcc * 4096 + nh * 2048 + ((tid >> 6) & 3) * 512;
        gld_lds16(src, dst);
    }
}

__device__ __forceinline__ bf16x8 ldfrag(const unsigned short* S, int row, int ks,
                                         int quad, int ln15) {
    int gr = ((ks << 2) | quad) ^ (ln15 & 7);
    return *(const bf16x8*)(S + row * 64 + gr * 8);
}

#define PHASE_SYNC()                                        \
    __builtin_amdgcn_s_barrier();                           \
    asm volatile("s_waitcnt lgkmcnt(0)" ::: "memory");      \
    __builtin_amdgcn_sched_barrier(0);                      \
    __builtin_amdgcn_s_setprio(1)

#define PHASE_END()                                         \
    __builtin_amdgcn_s_setprio(0);                          \
    asm volatile("s_waitcnt vmcnt(4)" ::: "memory");        \
    __builtin_amdgcn_s_barrier()

__device__ __forceinline__ void qkv_tile(
        const unsigned short* __restrict__ Ag, const unsigned short* __restrict__ Bg,
        unsigned short* Asc, unsigned short* Bsc,
        unsigned short* Asn, unsigned short* Bsn,
        int t, int m0, int n0, int tid, int wr, int wc, int ln15, int quad,
        floatx4 (&acc)[8][4]) {
    bf16x8 a[4][2], bb[2][2];
    bool pf = (t + 1 < NT_QKV);
    // ---- phase 0
#pragma unroll
    for (int m = 0; m < 4; m++) {
        a[m][0] = ldfrag(Asc, wr * 128 + m * 16 + ln15, 0, quad, ln15);
        a[m][1] = ldfrag(Asc, wr * 128 + m * 16 + ln15, 1, quad, ln15);
    }
#pragma unroll
    for (int n = 0; n < 2; n++) {
        bb[n][0] = ldfrag(Bsc, wc * 64 + n * 16 + ln15, 0, quad, ln15);
        bb[n][1] = ldfrag(Bsc, wc * 64 + n * 16 + ln15, 1, quad, ln15);
    }
    if (pf) stage_B(Bg, Bsn, 0, n0, t + 1, tid);
    PHASE_SYNC();
#pragma unroll
    for (int m = 0; m < 4; m++)
#pragma unroll
        for (int n = 0; n < 2; n++) {
            acc[m][n] = MFMA16(a[m][0], bb[n][0], acc[m][n]);
            acc[m][n] = MFMA16(a[m][1], bb[n][1], acc[m][n]);
        }
    PHASE_END();
    // ---- phase 1
#pragma unroll
    for (int n = 0; n < 2; n++) {
        bb[n][0] = ldfrag(Bsc, wc * 64 + (2 + n) * 16 + ln15, 0, quad, ln15);
        bb[n][1] = ldfrag(Bsc, wc * 64 + (2 + n) * 16 + ln15, 1, quad, ln15);
    }
    if (pf) stage_A(Ag, Asn, 0, m0, t + 1, tid);
    PHASE_SYNC();
#pragma unroll
    for (int m = 0; m < 4; m++)
#pragma unroll
        for (int n = 0; n < 2; n++) {
            acc[m][2 + n] = MFMA16(a[m][0], bb[n][0], acc[m][2 + n]);
            acc[m][2 + n] = MFMA16(a[m][1], bb[n][1], acc[m][2 + n]);
        }
    PHASE_END();
    // ---- phase 2
#pragma unroll
    for (int m = 0; m < 4; m++) {
        a[m][0] = ldfrag(Asc, wr * 128 + (4 + m) * 16 + ln15, 0, quad, ln15);
        a[m][1] = ldfrag(Asc, wr * 128 + (4 + m) * 16 + ln15, 1, quad, ln15);
    }
    if (pf) stage_B(Bg, Bsn, 1, n0, t + 1, tid);
    PHASE_SYNC();
#pragma unroll
    for (int m = 0; m < 4; m++)
#pragma unroll
        for (int n = 0; n < 2; n++) {
            acc[4 + m][2 + n] = MFMA16(a[m][0], bb[n][0], acc[4 + m][2 + n]);
            acc[4 + m][2 + n] = MFMA16(a[m][1], bb[n][1], acc[4 + m][2 + n]);
        }
    PHASE_END();
    // ---- phase 3
#pragma unroll
    for (int n = 0; n < 2; n++) {
        bb[n][0] = ldfrag(Bsc, wc * 64 + n * 16 + ln15, 0, quad, ln15);
        bb[n][1] = ldfrag(Bsc, wc * 64 + n * 16 + ln15, 1, quad, ln15);
    }
    if (pf) stage_A(Ag, Asn, 1, m0, t + 1, tid);
    PHASE_SYNC();
#pragma unroll
    for (int m = 0; m < 4; m++)
#pragma unroll
        for (int n = 0; n < 2; n++) {
            acc[4 + m][n] = MFMA16(a[m][0], bb[n][0], acc[4 + m][n]);
            acc[4 + m][n] = MFMA16(a[m][1], bb[n][1], acc[4 + m][n]);
        }
    PHASE_END();
}

__global__ __launch_bounds__(512, 2) void gemm_qkv(
        const unsigned short* __restrict__ A, const unsigned short* __restrict__ Bt,
        const float* __restrict__ bias, float* __restrict__ ko,
        float* __restrict__ vo, unsigned short* __restrict__ qws,
        unsigned short* __restrict__ kbf) {
    __shared__ __align__(16) unsigned short As[2][16384];
    __shared__ __align__(16) unsigned short Bs[2][16384];
    int bid = blockIdx.x;
    int xcd = bid & 7, idx = bid >> 3;
    int mt = (xcd & 3) * 4 + idx / 12;
    int ntile = (xcd >> 2) * 12 + idx % 12;
    int m0 = mt * 256, n0 = ntile * 256;
    int tid = threadIdx.x;
    int wave = tid >> 6, lane = tid & 63, ln15 = lane & 15, quad = lane >> 4;
    int wr = wave >> 2, wc = wave & 3;
    floatx4 acc[8][4] = {};
    stage_B(Bt, Bs[0], 0, n0, 0, tid);
    stage_A(A, As[0], 0, m0, 0, tid);
    stage_B(Bt, Bs[0], 1, n0, 0, tid);
    stage_A(A, As[0], 1, m0, 0, tid);
    asm volatile("s_waitcnt vmcnt(4)" ::: "memory");
    __builtin_amdgcn_s_barrier();
#pragma unroll 1
    for (int t = 0; t < NT_QKV; t += 2) {
        qkv_tile(A, Bt, As[0], Bs[0], As[1], Bs[1], t,     m0, n0, tid, wr, wc, ln15, quad, acc);
        qkv_tile(A, Bt, As[1], Bs[1], As[0], Bs[0], t + 1, m0, n0, tid, wr, wc, ln15, quad, acc);
    }
#pragma unroll
    for (int mi = 0; mi < 8; mi++) {
        int row = m0 + wr * 128 + mi * 16 + quad * 4;
#pragma unroll
        for (int ni = 0; ni < 4; ni++) {
            int col = n0 + wc * 64 + ni * 16 + ln15;
            float bv = bias[col];
#pragma unroll
            for (int r = 0; r < 4; r++) {
                float val = acc[mi][ni][r] + bv;
                int rr = row + r;
                int b = rr >> 11, s = rr & 2047;
                if (col < 2048) {
                    qws[(size_t)rr * 2048 + col] = f2bf(val);
                } else if (col < 4096) {
                    int cc = col - 2048; int h = cc >> 7, d = cc & 127;
                    size_t o = ((size_t)(b * 16 + h) * 2048 + s) * 128 + d;
                    ko[o] = val;
                    kbf[o] = f2bf(val);
                } else {
                    int cc = col - 4096; int h = cc >> 7, d = cc & 127;
                    vo[((size_t)(b * 16 + h) * 2048 + s) * 128 + d] = val;
                }
            }
        }
    }
}

// ------------------------------------------------------------- output GEMM
__global__ __launch_bounds__(256) void gemm_out(
        const float* __restrict__ Actx, const unsigned short* __restrict__ Bt,
        float* __restrict__ out) {
    __shared__ unsigned short As[128 * 72];
    __shared__ unsigned short Bs[128 * 72];
    int m0 = blockIdx.y * 128, n0 = blockIdx.x * 128;
    int t = threadIdx.x;
    int wave = t >> 6, lane = t & 63, ln15 = lane & 15, quad = lane >> 4;
    int wm = wave >> 1, wn = wave & 1;
    floatx4 acc[4][4] = {};
    for (int k0 = 0; k0 < 2048; k0 += 64) {
        for (int p = 0; p < 4; p++) {
            int idx = p * 256 + t; int r = idx >> 3; int c = (idx & 7) * 8;
            const float* ap = Actx + (size_t)(m0 + r) * 2048 + k0 + c;
            float4 u0 = ((const float4*)ap)[0], u1 = ((const float4*)ap)[1];
            union { unsigned short u[8]; uint4 v; } pk;
            pk.u[0] = f2bf(u0.x); pk.u[1] = f2bf(u0.y); pk.u[2] = f2bf(u0.z); pk.u[3] = f2bf(u0.w);
            pk.u[4] = f2bf(u1.x); pk.u[5] = f2bf(u1.y); pk.u[6] = f2bf(u1.z); pk.u[7] = f2bf(u1.w);
            *(uint4*)&As[r * 72 + c] = pk.v;
            *(uint4*)&Bs[r * 72 + c] = *(const uint4*)(Bt + (size_t)(n0 + r) * 2048 + k0 + c);
        }
        __syncthreads();
        for (int ks = 0; ks < 2; ks++) {
            bf16x8 af[4], bfr[4];
            for (int i = 0; i < 4; i++)
                af[i] = *(const bf16x8*)&As[(wm * 64 + i * 16 + ln15) * 72 + ks * 32 + quad * 8];
            for (int i = 0; i < 4; i++)
                bfr[i] = *(const bf16x8*)&Bs[(wn * 64 + i * 16 + ln15) * 72 + ks * 32 + quad * 8];
            for (int mi = 0; mi < 4; mi++)
                for (int ni = 0; ni < 4; ni++)
                    acc[mi][ni] = MFMA16(af[mi], bfr[ni], acc[mi][ni]);
        }
        __syncthreads();
    }
    for (int mi = 0; mi < 4; mi++) {
        int row = m0 + wm * 64 + mi * 16 + quad * 4;
        for (int ni = 0; ni < 4; ni++) {
            int col = n0 + wn * 64 + ni * 16 + ln15;
            for (int r = 0; r < 4; r++)
                out[(size_t)(row + r) * 2048 + col] = acc[mi][ni][r];
        }
    }
}

// ---------------------------------------------------------- flash attention
// Balanced (jp, 31-jp) pairing, 4 waves. K/V staged via global_load_lds into
// DOUBLE-BUFFERED unpadded LDS with XOR granule swizzle (slot = g ^ (row&7)),
// applied as inverse-swizzled global source + same XOR on ds_read (rule 21).
// Counted vmcnt(8) pipeline (8 gld_lds/thread/tile); raw s_barrier (no
// __syncthreads -> would drain vmcnt). T13 defer-max, T5 setprio kept.
__device__ __forceinline__ void stage_kv(const unsigned short* __restrict__ kb,
                                         const unsigned short* __restrict__ vTb,
                                         int c0, int tid,
                                         unsigned short* KsB, unsigned short* VtB) {
    int wb = (tid >> 6) << 6;  // wave base granule
#pragma unroll
    for (int i = 0; i < 4; i++) {             // K: 64 rows x 16 granules
        int p = i * 256 + tid;
        int r = p >> 4, s = p & 15;
        int g = s ^ (r & 7);
        gld_lds16(kb + (size_t)(c0 + r) * 128 + g * 8, KsB + (i * 256 + wb) * 8);
    }
#pragma unroll
    for (int i = 0; i < 4; i++) {             // V: 128 rows x 8 granules
        int p = i * 256 + tid;
        int d = p >> 3, s = p & 7;
        int g = s ^ (d & 7);
        gld_lds16(vTb + (size_t)d * 2048 + c0 + g * 8, VtB + (i * 256 + wb) * 8);
    }
}

__global__ __launch_bounds__(256, 2) void attn_kernel(
        const unsigned short* __restrict__ qws, const unsigned short* __restrict__ kbf,
        const unsigned short* __restrict__ vT, const float* __restrict__ mask,
        float* __restrict__ ctxo) {
    __shared__ __align__(16) unsigned short Ks[2][64 * 128];
    __shared__ __align__(16) unsigned short Vt[2][128 * 64];
    __shared__ unsigned short Pl[4 * 16 * 72];
    int jp = blockIdx.x, h = blockIdx.y, b = blockIdx.z;
    int t = threadIdx.x, wave = t >> 6, lane = t & 63, ln15 = lane & 15, quad = lane >> 4;
    int x7 = ln15 & 7;
    const float scale = 0.08838834764831845f;  // 1/sqrt(128)

    const unsigned short* kb = kbf + (size_t)(b * 16 + h) * 2048 * 128;
    const unsigned short* vTb = vT + (size_t)(b * 16 + h) * 128 * 2048;
    const float* mb = mask + (size_t)b * 2048;

    int cur = 0;
    stage_kv(kb, vTb, 0, t, Ks[0], Vt[0]);  // prologue: half-0 tile 0

#pragma unroll 1
    for (int half = 0; half < 2; half++) {
        int qt = half ? (31 - jp) : jp;
        int Q0 = qt * 64;

        bf16x8 qf[4];
        const unsigned short* qbase =
            qws + ((size_t)(b * 2048 + Q0 + wave * 16 + ln15)) * 2048 + h * 128;
#pragma unroll
        for (int ks = 0; ks < 4; ks++)
            qf[ks] = *(const bf16x8*)(qbase + ks * 32 + quad * 8);

        float m_r[4], l_r[4];
        floatx4 o[8] = {};
#pragma unroll
        for (int r = 0; r < 4; r++) { m_r[r] = -1e30f; l_r[r] = 0.0f; }

        int nkt = qt + 1;
#pragma unroll 1
        for (int kt = 0; kt < nkt; kt++) {
            int c0 = kt * 64;
            // stage next tile into other buffer; counted wait for CUR tile
            bool hn = true; int nc0 = 0;
            if (kt + 1 < nkt)      nc0 = c0 + 64;
            else if (half == 0)    nc0 = 0;        // half-1 tile 0
            else                   hn = false;
            if (hn) {
                stage_kv(kb, vTb, nc0, t, Ks[cur ^ 1], Vt[cur ^ 1]);
                asm volatile("s_waitcnt vmcnt(8)" ::: "memory");
            } else {
                asm volatile("s_waitcnt vmcnt(0)" ::: "memory");
            }
            __builtin_amdgcn_s_barrier();   // cur visible to all waves
            const unsigned short* KsB = Ks[cur];
            const unsigned short* VtB = Vt[cur];

            // S = Q @ K^T  (16 x 64 per wave), swizzled K reads
            floatx4 cs[4] = {};
            __builtin_amdgcn_s_setprio(1);
#pragma unroll
            for (int ks = 0; ks < 4; ks++)
#pragma unroll
                for (int ni = 0; ni < 4; ni++) {
                    int rr = ni * 16 + ln15;
                    int sl = (ks * 4 + quad) ^ x7;
                    bf16x8 kfr = *(const bf16x8*)&KsB[rr * 128 + sl * 8];
                    cs[ni] = MFMA16(qf[ks], kfr, cs[ni]);
                }
            __builtin_amdgcn_s_setprio(0);

            // scale + mask + row max
            float sv[4][4];
            float mt[4] = {-1e30f, -1e30f, -1e30f, -1e30f};
            if (kt == qt) {
#pragma unroll
                for (int ni = 0; ni < 4; ni++) {
                    int cg = c0 + ni * 16 + ln15;
                    float mk = mb[cg];
#pragma unroll
                    for (int r = 0; r < 4; r++) {
                        int qg = Q0 + wave * 16 + quad * 4 + r;
                        float v = (cg <= qg) ? fmaf(cs[ni][r], scale, mk) : -10000.0f;
                        sv[ni][r] = v;
                        mt[r] = fmaxf(mt[r], v);
                    }
                }
            } else {
#pragma unroll
                for (int ni = 0; ni < 4; ni++) {
                    float mk = mb[c0 + ni * 16 + ln15];
#pragma unroll
                    for (int r = 0; r < 4; r++) {
                        float v = fmaf(cs[ni][r], scale, mk);
                        sv[ni][r] = v;
                        mt[r] = fmaxf(mt[r], v);
                    }
                }
            }
#pragma unroll
            for (int m = 1; m < 16; m <<= 1)
#pragma unroll
                for (int r = 0; r < 4; r++) mt[r] = fmaxf(mt[r], __shfl_xor(mt[r], m));

            // T13 defer-max
            bool grow = false;
#pragma unroll
            for (int r = 0; r < 4; r++) grow = grow || (mt[r] > m_r[r] + 8.0f);
            if (__any((int)grow)) {
#pragma unroll
                for (int r = 0; r < 4; r++) {
                    float mn = fmaxf(m_r[r], mt[r]);
                    float al = __expf(m_r[r] - mn);
                    m_r[r] = mn;
                    l_r[r] *= al;
#pragma unroll
                    for (int nj = 0; nj < 8; nj++) o[nj][r] *= al;
                }
            }

            // P = exp(s - m), row sums
            float lt[4] = {0.0f, 0.0f, 0.0f, 0.0f};
#pragma unroll
            for (int ni = 0; ni < 4; ni++)
#pragma unroll
                for (int r = 0; r < 4; r++) {
                    float p = __expf(sv[ni][r] - m_r[r]);
                    sv[ni][r] = p;
                    lt[r] += p;
                }
#pragma unroll
            for (int m = 1; m < 16; m <<= 1)
#pragma unroll
                for (int r = 0; r < 4; r++) lt[r] += __shfl_xor(lt[r], m);
#pragma unroll
            for (int r = 0; r < 4; r++) l_r[r] += lt[r];

            // P (C-layout) -> LDS -> A-layout (wave-private region)
            unsigned short* pw = &Pl[wave * 16 * 72];
#pragma unroll
            for (int ni = 0; ni < 4; ni++)
#pragma unroll
                for (int r = 0; r < 4; r++)
                    pw[(quad * 4 + r) * 72 + ni * 16 + ln15] = f2bf(sv[ni][r]);

            // O += P @ V, swizzled V reads
            __builtin_amdgcn_s_setprio(1);
#pragma unroll
            for (int ks2 = 0; ks2 < 2; ks2++) {
                bf16x8 pf = *(const bf16x8*)&Pl[(wave * 16 + ln15) * 72 + ks2 * 32 + quad * 8];
#pragma unroll
                for (int nj = 0; nj < 8; nj++) {
                    int dd = nj * 16 + ln15;
                    int sl = (ks2 * 4 + quad) ^ x7;
                    bf16x8 vf = *(const bf16x8*)&VtB[dd * 64 + sl * 8];
                    o[nj] = MFMA16(pf, vf, o[nj]);
                }
            }
            __builtin_amdgcn_s_setprio(0);
            __builtin_amdgcn_s_barrier();   // all reads of cur done -> reusable
            cur ^= 1;
        }

        float rl[4];
#pragma unroll
        for (int r = 0; r < 4; r++) rl[r] = 1.0f / l_r[r];
#pragma unroll
        for (int nj = 0; nj < 8; nj++)
#pragma unroll
            for (int r = 0; r < 4; r++) {
                int s = Q0 + wave * 16 + quad * 4 + r;
                ctxo[((size_t)(b * 2048 + s)) * 2048 + h * 128 + nj * 16 + ln15] = o[nj][r] * rl[r];
            }
    }
}

extern "C" void kernel_launch(void* const* d_in, const int* in_sizes, int n_in,
                              void* d_out, int out_size, void* d_ws, size_t ws_size,
                              hipStream_t stream) {
    const float* x      = (const float*)d_in[0];
    const float* mask   = (const float*)d_in[1];
    const float* qkvw   = (const float*)d_in[2];
    const float* qkvb   = (const float*)d_in[3];
    const float* ow     = (const float*)d_in[4];
    const float* norm_w = (const float*)d_in[5];
    const float* norm_b = (const float*)d_in[6];

    float* out      = (float*)d_out;             // [B,S,H]
    float* k_out    = out + 8388608;             // [B,Hd,S,dh]
    float* v_out    = out + 16777216;            // [B,Hd,S,dh]
    float* ctx_out  = out + 25165824;            // [B,S,H]
    float* norm_out = out + 33554432;            // [B,S,H]

    unsigned short* ws    = (unsigned short*)d_ws;
    unsigned short* xn    = ws;                        // 8,388,608  bf16
    unsigned short* qkvwT = ws + 8388608;              // 12,582,912 bf16 [6144][2048]
    unsigned short* owT   = ws + 8388608 + 12582912;   // 4,194,304  bf16 [2048][2048]
    unsigned short* qws   = owT + 4194304;             // 8,388,608  bf16 [B*S][H]
    unsigned short* vT    = qws + 8388608;             // 8,388,608  bf16 [B*Hd][dh][S]
    unsigned short* kbf   = vT + 8388608;              // 8,388,608  bf16 [B*Hd][S][dh]

    ln_kernel<<<4096, 256, 0, stream>>>(x, norm_w, norm_b, norm_out, xn);
    transpose_cvt<<<dim3(96, 32, 1), 256, 0, stream>>>(qkvw, qkvwT, 2048, 6144);
    transpose_cvt<<<dim3(32, 32, 1), 256, 0, stream>>>(ow, owT, 2048, 2048);
    gemm_qkv<<<dim3(384), 512, 0, stream>>>(xn, qkvwT, qkvb, k_out, v_out, qws, kbf);
    transpose_cvt<<<dim3(2, 32, 32), 256, 0, stream>>>(v_out, vT, 2048, 128);
    attn_kernel<<<dim3(16, 16, 2), 256, 0, stream>>>(qws, kbf, vT, mask, ctx_out);
    gemm_out<<<dim3(16, 32), 256, 0, stream>>>(ctx_out, owT, out);
}

// Round 8
// 542.636 us; speedup vs baseline: 1.2568x; 1.0147x over previous
//
#include <hip/hip_runtime.h>

typedef short bf16x8 __attribute__((ext_vector_type(8)));
typedef float floatx4 __attribute__((ext_vector_type(4)));

#define MFMA16(a, b, c) __builtin_amdgcn_mfma_f32_16x16x32_bf16((a), (b), (c), 0, 0, 0)

__device__ __forceinline__ unsigned short f2bf(float f) {
    union { float f; unsigned int u; } v; v.f = f;
    unsigned int u = v.u;
    return (unsigned short)((u + 0x7FFFu + ((u >> 16) & 1u)) >> 16);
}

// async global->LDS, 16B per lane; lds base must be wave-uniform (m97 pattern)
__device__ __forceinline__ void gld_lds16(const void* g, void* l) {
    __builtin_amdgcn_global_load_lds(
        (const __attribute__((address_space(1))) unsigned int*)g,
        (__attribute__((address_space(3))) unsigned int*)l, 16, 0, 0);
}

// ---------------------------------------------------- fused prep kernel
// blocks [0,4096): LayerNorm rows; [4096,7168): qkvw transpose; [7168,8192): ow
__global__ __launch_bounds__(256) void prep_kernel(
        const float* __restrict__ x, const float* __restrict__ g,
        const float* __restrict__ be, float* __restrict__ yo,
        unsigned short* __restrict__ yb,
        const float* __restrict__ qkvw, unsigned short* __restrict__ qkvwT,
        const float* __restrict__ ow, unsigned short* __restrict__ owT) {
    __shared__ float red[8];
    __shared__ unsigned short tile[64][73];
    int bid = blockIdx.x, t = threadIdx.x;
    if (bid < 4096) {
        // ---- LayerNorm
        int row = bid;
        const float* xr = x + (size_t)row * 2048;
        float4 a = ((const float4*)xr)[2 * t];
        float4 b = ((const float4*)xr)[2 * t + 1];
        float s = a.x + a.y + a.z + a.w + b.x + b.y + b.z + b.w;
        float q = a.x * a.x + a.y * a.y + a.z * a.z + a.w * a.w +
                  b.x * b.x + b.y * b.y + b.z * b.z + b.w * b.w;
        for (int m = 1; m < 64; m <<= 1) { s += __shfl_xor(s, m); q += __shfl_xor(q, m); }
        if ((t & 63) == 0) { red[t >> 6] = s; red[4 + (t >> 6)] = q; }
        __syncthreads();
        s = red[0] + red[1] + red[2] + red[3];
        q = red[4] + red[5] + red[6] + red[7];
        float mean = s * (1.0f / 2048.0f);
        float var = q * (1.0f / 2048.0f) - mean * mean;
        float rs = rsqrtf(var + 1e-12f);
        float4 g0 = ((const float4*)g)[2 * t], g1 = ((const float4*)g)[2 * t + 1];
        float4 b0 = ((const float4*)be)[2 * t], b1 = ((const float4*)be)[2 * t + 1];
        float4 y0, y1;
        y0.x = (a.x - mean) * rs * g0.x + b0.x;
        y0.y = (a.y - mean) * rs * g0.y + b0.y;
        y0.z = (a.z - mean) * rs * g0.z + b0.z;
        y0.w = (a.w - mean) * rs * g0.w + b0.w;
        y1.x = (b.x - mean) * rs * g1.x + b1.x;
        y1.y = (b.y - mean) * rs * g1.y + b1.y;
        y1.z = (b.z - mean) * rs * g1.z + b1.z;
        y1.w = (b.w - mean) * rs * g1.w + b1.w;
        float* yr = yo + (size_t)row * 2048;
        ((float4*)yr)[2 * t] = y0;
        ((float4*)yr)[2 * t + 1] = y1;
        union { unsigned short u[8]; uint4 v; } pk;
        pk.u[0] = f2bf(y0.x); pk.u[1] = f2bf(y0.y); pk.u[2] = f2bf(y0.z); pk.u[3] = f2bf(y0.w);
        pk.u[4] = f2bf(y1.x); pk.u[5] = f2bf(y1.y); pk.u[6] = f2bf(y1.z); pk.u[7] = f2bf(y1.w);
        *(uint4*)(yb + (size_t)row * 2048 + t * 8) = pk.v;
        return;
    }
    // ---- weight transpose fp32 -> bf16
    const float* src; unsigned short* dst; int N, n0, k0;
    if (bid < 4096 + 3072) {
        int b2 = bid - 4096;
        src = qkvw; dst = qkvwT; N = 6144;
        n0 = (b2 % 96) * 64; k0 = (b2 / 96) * 64;
    } else {
        int b3 = bid - 7168;
        src = ow; dst = owT; N = 2048;
        n0 = (b3 % 32) * 64; k0 = (b3 / 32) * 64;
    }
    for (int p = 0; p < 4; p++) {
        int idx = p * 256 + t; int r = idx >> 4; int c = (idx & 15) * 4;
        float4 v = *(const float4*)(src + (size_t)(k0 + r) * N + n0 + c);
        tile[r][c] = f2bf(v.x); tile[r][c + 1] = f2bf(v.y);
        tile[r][c + 2] = f2bf(v.z); tile[r][c + 3] = f2bf(v.w);
    }
    __syncthreads();
    for (int p = 0; p < 4; p++) {
        int idx = p * 256 + t; int n = idx >> 4; int c = (idx & 15) * 4;
        ushort4 o;
        o.x = tile[c][n]; o.y = tile[c + 1][n];
        o.z = tile[c + 2][n]; o.w = tile[c + 3][n];
        *(ushort4*)(dst + (size_t)(n0 + n) * 2048 + k0 + c) = o;
    }
}

// ------------------------------------------- batched transpose fp32 -> bf16
__global__ __launch_bounds__(256) void transpose_cvt(
        const float* __restrict__ src, unsigned short* __restrict__ dst,
        int K, int N) {
    __shared__ unsigned short tile[64][73];
    int n0 = blockIdx.x * 64, k0 = blockIdx.y * 64;
    size_t bo = (size_t)blockIdx.z * K * N;
    int t = threadIdx.x;
    for (int p = 0; p < 4; p++) {
        int idx = p * 256 + t; int r = idx >> 4; int c = (idx & 15) * 4;
        float4 v = *(const float4*)(src + bo + (size_t)(k0 + r) * N + n0 + c);
        tile[r][c] = f2bf(v.x); tile[r][c + 1] = f2bf(v.y);
        tile[r][c + 2] = f2bf(v.z); tile[r][c + 3] = f2bf(v.w);
    }
    __syncthreads();
    for (int p = 0; p < 4; p++) {
        int idx = p * 256 + t; int n = idx >> 4; int c = (idx & 15) * 4;
        ushort4 o;
        o.x = tile[c][n]; o.y = tile[c + 1][n];
        o.z = tile[c + 2][n]; o.w = tile[c + 3][n];
        *(ushort4*)(dst + bo + (size_t)(n0 + n) * K + k0 + c) = o;
    }
}

// ================================================================ QKV GEMM
// 256x256 tile, BK=64, 8 waves (2M x 4N), 8-phase schedule, alias-clean NXT
// staging, uniform vmcnt(4). Best measured variant (164.5 us) — kept as-is.
#define NT_QKV 32

__device__ __forceinline__ void stage_A(const unsigned short* __restrict__ Ag,
        unsigned short* As, int mh, int m0, int kt, int tid) {
#pragma unroll
    for (int j = 0; j < 2; j++) {
        int G = j * 512 + tid;
        int s = (G >> 3) & 63;
        int gr = G & 7;
        int row = j * 128 + mh * 64 + s;
        const unsigned short* src =
            Ag + (size_t)(m0 + row) * 2048 + kt * 64 + ((gr ^ (s & 7)) << 3);
        unsigned short* dst = As + j * 8192 + mh * 4096 + (tid >> 6) * 512;
        gld_lds16(src, dst);
    }
}

__device__ __forceinline__ void stage_B(const unsigned short* __restrict__ Bg,
        unsigned short* Bs, int nh, int n0, int kt, int tid) {
#pragma unroll
    for (int j = 0; j < 2; j++) {
        int G = j * 512 + tid;
        int wcc = G >> 8;
        int s = (G >> 3) & 31;
        int gr = G & 7;
        int row = wcc * 64 + nh * 32 + s;
        const unsigned short* src =
            Bg + (size_t)(n0 + row) * 2048 + kt * 64 + ((gr ^ (s & 7)) << 3);
        unsigned short* dst = Bs + wcc * 4096 + nh * 2048 + ((tid >> 6) & 3) * 512;
        gld_lds16(src, dst);
    }
}

__device__ __forceinline__ bf16x8 ldfrag(const unsigned short* S, int row, int ks,
                                         int quad, int ln15) {
    int gr = ((ks << 2) | quad) ^ (ln15 & 7);
    return *(const bf16x8*)(S + row * 64 + gr * 8);
}

#define PHASE_SYNC()                                        \
    __builtin_amdgcn_s_barrier();                           \
    asm volatile("s_waitcnt lgkmcnt(0)" ::: "memory");      \
    __builtin_amdgcn_sched_barrier(0);                      \
    __builtin_amdgcn_s_setprio(1)

#define PHASE_END()                                         \
    __builtin_amdgcn_s_setprio(0);                          \
    asm volatile("s_waitcnt vmcnt(4)" ::: "memory");        \
    __builtin_amdgcn_s_barrier()

__device__ __forceinline__ void qkv_tile(
        const unsigned short* __restrict__ Ag, const unsigned short* __restrict__ Bg,
        unsigned short* Asc, unsigned short* Bsc,
        unsigned short* Asn, unsigned short* Bsn,
        int t, int m0, int n0, int tid, int wr, int wc, int ln15, int quad,
        floatx4 (&acc)[8][4]) {
    bf16x8 a[4][2], bb[2][2];
    bool pf = (t + 1 < NT_QKV);
    // ---- phase 0
#pragma unroll
    for (int m = 0; m < 4; m++) {
        a[m][0] = ldfrag(Asc, wr * 128 + m * 16 + ln15, 0, quad, ln15);
        a[m][1] = ldfrag(Asc, wr * 128 + m * 16 + ln15, 1, quad, ln15);
    }
#pragma unroll
    for (int n = 0; n < 2; n++) {
        bb[n][0] = ldfrag(Bsc, wc * 64 + n * 16 + ln15, 0, quad, ln15);
        bb[n][1] = ldfrag(Bsc, wc * 64 + n * 16 + ln15, 1, quad, ln15);
    }
    if (pf) stage_B(Bg, Bsn, 0, n0, t + 1, tid);
    PHASE_SYNC();
#pragma unroll
    for (int m = 0; m < 4; m++)
#pragma unroll
        for (int n = 0; n < 2; n++) {
            acc[m][n] = MFMA16(a[m][0], bb[n][0], acc[m][n]);
            acc[m][n] = MFMA16(a[m][1], bb[n][1], acc[m][n]);
        }
    PHASE_END();
    // ---- phase 1
#pragma unroll
    for (int n = 0; n < 2; n++) {
        bb[n][0] = ldfrag(Bsc, wc * 64 + (2 + n) * 16 + ln15, 0, quad, ln15);
        bb[n][1] = ldfrag(Bsc, wc * 64 + (2 + n) * 16 + ln15, 1, quad, ln15);
    }
    if (pf) stage_A(Ag, Asn, 0, m0, t + 1, tid);
    PHASE_SYNC();
#pragma unroll
    for (int m = 0; m < 4; m++)
#pragma unroll
        for (int n = 0; n < 2; n++) {
            acc[m][2 + n] = MFMA16(a[m][0], bb[n][0], acc[m][2 + n]);
            acc[m][2 + n] = MFMA16(a[m][1], bb[n][1], acc[m][2 + n]);
        }
    PHASE_END();
    // ---- phase 2
#pragma unroll
    for (int m = 0; m < 4; m++) {
        a[m][0] = ldfrag(Asc, wr * 128 + (4 + m) * 16 + ln15, 0, quad, ln15);
        a[m][1] = ldfrag(Asc, wr * 128 + (4 + m) * 16 + ln15, 1, quad, ln15);
    }
    if (pf) stage_B(Bg, Bsn, 1, n0, t + 1, tid);
    PHASE_SYNC();
#pragma unroll
    for (int m = 0; m < 4; m++)
#pragma unroll
        for (int n = 0; n < 2; n++) {
            acc[4 + m][2 + n] = MFMA16(a[m][0], bb[n][0], acc[4 + m][2 + n]);
            acc[4 + m][2 + n] = MFMA16(a[m][1], bb[n][1], acc[4 + m][2 + n]);
        }
    PHASE_END();
    // ---- phase 3
#pragma unroll
    for (int n = 0; n < 2; n++) {
        bb[n][0] = ldfrag(Bsc, wc * 64 + n * 16 + ln15, 0, quad, ln15);
        bb[n][1] = ldfrag(Bsc, wc * 64 + n * 16 + ln15, 1, quad, ln15);
    }
    if (pf) stage_A(Ag, Asn, 1, m0, t + 1, tid);
    PHASE_SYNC();
#pragma unroll
    for (int m = 0; m < 4; m++)
#pragma unroll
        for (int n = 0; n < 2; n++) {
            acc[4 + m][n] = MFMA16(a[m][0], bb[n][0], acc[4 + m][n]);
            acc[4 + m][n] = MFMA16(a[m][1], bb[n][1], acc[4 + m][n]);
        }
    PHASE_END();
}

__global__ __launch_bounds__(512, 2) void gemm_qkv(
        const unsigned short* __restrict__ A, const unsigned short* __restrict__ Bt,
        const float* __restrict__ bias, float* __restrict__ ko,
        float* __restrict__ vo, unsigned short* __restrict__ qws,
        unsigned short* __restrict__ kbf) {
    __shared__ __align__(16) unsigned short As[2][16384];
    __shared__ __align__(16) unsigned short Bs[2][16384];
    int bid = blockIdx.x;
    int xcd = bid & 7, idx = bid >> 3;
    int mt = (xcd & 3) * 4 + idx / 12;
    int ntile = (xcd >> 2) * 12 + idx % 12;
    int m0 = mt * 256, n0 = ntile * 256;
    int tid = threadIdx.x;
    int wave = tid >> 6, lane = tid & 63, ln15 = lane & 15, quad = lane >> 4;
    int wr = wave >> 2, wc = wave & 3;
    floatx4 acc[8][4] = {};
    stage_B(Bt, Bs[0], 0, n0, 0, tid);
    stage_A(A, As[0], 0, m0, 0, tid);
    stage_B(Bt, Bs[0], 1, n0, 0, tid);
    stage_A(A, As[0], 1, m0, 0, tid);
    asm volatile("s_waitcnt vmcnt(4)" ::: "memory");
    __builtin_amdgcn_s_barrier();
#pragma unroll 1
    for (int t = 0; t < NT_QKV; t += 2) {
        qkv_tile(A, Bt, As[0], Bs[0], As[1], Bs[1], t,     m0, n0, tid, wr, wc, ln15, quad, acc);
        qkv_tile(A, Bt, As[1], Bs[1], As[0], Bs[0], t + 1, m0, n0, tid, wr, wc, ln15, quad, acc);
    }
#pragma unroll
    for (int mi = 0; mi < 8; mi++) {
        int row = m0 + wr * 128 + mi * 16 + quad * 4;
#pragma unroll
        for (int ni = 0; ni < 4; ni++) {
            int col = n0 + wc * 64 + ni * 16 + ln15;
            float bv = bias[col];
#pragma unroll
            for (int r = 0; r < 4; r++) {
                float val = acc[mi][ni][r] + bv;
                int rr = row + r;
                int b = rr >> 11, s = rr & 2047;
                if (col < 2048) {
                    qws[(size_t)rr * 2048 + col] = f2bf(val);
                } else if (col < 4096) {
                    int cc = col - 2048; int h = cc >> 7, d = cc & 127;
                    size_t o = ((size_t)(b * 16 + h) * 2048 + s) * 128 + d;
                    ko[o] = val;
                    kbf[o] = f2bf(val);
                } else {
                    int cc = col - 4096; int h = cc >> 7, d = cc & 127;
                    vo[((size_t)(b * 16 + h) * 2048 + s) * 128 + d] = val;
                }
            }
        }
    }
}

// ------------------------------------------------------------- output GEMM
// m97-style: both inputs bf16, global_load_lds width-16 staging, 128x128 tile,
// 512 blocks (bijective 8x8-rect XCD swizzle). A = ctx bf16 (written by attn).
__global__ __launch_bounds__(256) void gemm_out(
        const unsigned short* __restrict__ Ab, const unsigned short* __restrict__ Bt,
        float* __restrict__ out) {
    __shared__ unsigned short As[128 * 64];
    __shared__ unsigned short Bs[128 * 64];
    int bid = blockIdx.x;
    int xcd = bid & 7, idx = bid >> 3;           // idx in [0,64)
    int mt = (xcd & 3) * 8 + (idx >> 3);         // [0,32)
    int nt = (xcd >> 2) * 8 + (idx & 7);         // [0,16)
    int m0 = mt * 128, n0 = nt * 128;
    int t = threadIdx.x;
    int wave = t >> 6, lane = t & 63, ln15 = lane & 15, quad = lane >> 4;
    int wm = wave >> 1, wn = wave & 1;
    floatx4 acc[4][4] = {};
    for (int k0 = 0; k0 < 2048; k0 += 64) {
        for (int p = 0; p < 4; p++) {
            int ix = p * 256 + t; int r = ix >> 3; int c = (ix & 7) * 8;
            gld_lds16(Ab + (size_t)(m0 + r) * 2048 + k0 + c, As + p * 2048 + wave * 512);
            gld_lds16(Bt + (size_t)(n0 + r) * 2048 + k0 + c, Bs + p * 2048 + wave * 512);
        }
        __syncthreads();
        for (int ks = 0; ks < 2; ks++) {
            bf16x8 af[4], bfr[4];
            for (int i = 0; i < 4; i++)
                af[i] = *(const bf16x8*)&As[(wm * 64 + i * 16 + ln15) * 64 + ks * 32 + quad * 8];
            for (int i = 0; i < 4; i++)
                bfr[i] = *(const bf16x8*)&Bs[(wn * 64 + i * 16 + ln15) * 64 + ks * 32 + quad * 8];
            for (int mi = 0; mi < 4; mi++)
                for (int ni = 0; ni < 4; ni++)
                    acc[mi][ni] = MFMA16(af[mi], bfr[ni], acc[mi][ni]);
        }
        __syncthreads();
    }
    for (int mi = 0; mi < 4; mi++) {
        int row = m0 + wm * 64 + mi * 16 + quad * 4;
        for (int ni = 0; ni < 4; ni++) {
            int col = n0 + wn * 64 + ni * 16 + ln15;
            for (int r = 0; r < 4; r++)
                out[(size_t)(row + r) * 2048 + col] = acc[mi][ni][r];
        }
    }
}

// ---------------------------------------------------------- flash attention
// Balanced (jp, 31-jp) pairing, 4 waves, double-buffered gld_lds K/V with XOR
// granule swizzle + counted vmcnt(8). Also emits ctx as bf16 for gemm_out.
__device__ __forceinline__ void stage_kv(const unsigned short* __restrict__ kb,
                                         const unsigned short* __restrict__ vTb,
                                         int c0, int tid,
                                         unsigned short* KsB, unsigned short* VtB) {
    int wb = (tid >> 6) << 6;  // wave base granule
#pragma unroll
    for (int i = 0; i < 4; i++) {             // K: 64 rows x 16 granules
        int p = i * 256 + tid;
        int r = p >> 4, s = p & 15;
        int g = s ^ (r & 7);
        gld_lds16(kb + (size_t)(c0 + r) * 128 + g * 8, KsB + (i * 256 + wb) * 8);
    }
#pragma unroll
    for (int i = 0; i < 4; i++) {             // V: 128 rows x 8 granules
        int p = i * 256 + tid;
        int d = p >> 3, s = p & 7;
        int g = s ^ (d & 7);
        gld_lds16(vTb + (size_t)d * 2048 + c0 + g * 8, VtB + (i * 256 + wb) * 8);
    }
}

__global__ __launch_bounds__(256, 2) void attn_kernel(
        const unsigned short* __restrict__ qws, const unsigned short* __restrict__ kbf,
        const unsigned short* __restrict__ vT, const float* __restrict__ mask,
        float* __restrict__ ctxo, unsigned short* __restrict__ ctxb) {
    __shared__ __align__(16) unsigned short Ks[2][64 * 128];
    __shared__ __align__(16) unsigned short Vt[2][128 * 64];
    __shared__ unsigned short Pl[4 * 16 * 72];
    int jp = blockIdx.x, h = blockIdx.y, b = blockIdx.z;
    int t = threadIdx.x, wave = t >> 6, lane = t & 63, ln15 = lane & 15, quad = lane >> 4;
    int x7 = ln15 & 7;
    const float scale = 0.08838834764831845f;  // 1/sqrt(128)

    const unsigned short* kb = kbf + (size_t)(b * 16 + h) * 2048 * 128;
    const unsigned short* vTb = vT + (size_t)(b * 16 + h) * 128 * 2048;
    const float* mb = mask + (size_t)b * 2048;

    int cur = 0;
    stage_kv(kb, vTb, 0, t, Ks[0], Vt[0]);  // prologue: half-0 tile 0

#pragma unroll 1
    for (int half = 0; half < 2; half++) {
        int qt = half ? (31 - jp) : jp;
        int Q0 = qt * 64;

        bf16x8 qf[4];
        const unsigned short* qbase =
            qws + ((size_t)(b * 2048 + Q0 + wave * 16 + ln15)) * 2048 + h * 128;
#pragma unroll
        for (int ks = 0; ks < 4; ks++)
            qf[ks] = *(const bf16x8*)(qbase + ks * 32 + quad * 8);

        float m_r[4], l_r[4];
        floatx4 o[8] = {};
#pragma unroll
        for (int r = 0; r < 4; r++) { m_r[r] = -1e30f; l_r[r] = 0.0f; }

        int nkt = qt + 1;
#pragma unroll 1
        for (int kt = 0; kt < nkt; kt++) {
            int c0 = kt * 64;
            bool hn = true; int nc0 = 0;
            if (kt + 1 < nkt)      nc0 = c0 + 64;
            else if (half == 0)    nc0 = 0;        // half-1 tile 0
            else                   hn = false;
            if (hn) {
                stage_kv(kb, vTb, nc0, t, Ks[cur ^ 1], Vt[cur ^ 1]);
                asm volatile("s_waitcnt vmcnt(8)" ::: "memory");
            } else {
                asm volatile("s_waitcnt vmcnt(0)" ::: "memory");
            }
            __builtin_amdgcn_s_barrier();   // cur visible to all waves
            const unsigned short* KsB = Ks[cur];
            const unsigned short* VtB = Vt[cur];

            // S = Q @ K^T  (16 x 64 per wave), swizzled K reads
            floatx4 cs[4] = {};
            __builtin_amdgcn_s_setprio(1);
#pragma unroll
            for (int ks = 0; ks < 4; ks++)
#pragma unroll
                for (int ni = 0; ni < 4; ni++) {
                    int rr = ni * 16 + ln15;
                    int sl = (ks * 4 + quad) ^ x7;
                    bf16x8 kfr = *(const bf16x8*)&KsB[rr * 128 + sl * 8];
                    cs[ni] = MFMA16(qf[ks], kfr, cs[ni]);
                }
            __builtin_amdgcn_s_setprio(0);

            // scale + mask + row max
            float sv[4][4];
            float mt[4] = {-1e30f, -1e30f, -1e30f, -1e30f};
            if (kt == qt) {
#pragma unroll
                for (int ni = 0; ni < 4; ni++) {
                    int cg = c0 + ni * 16 + ln15;
                    float mk = mb[cg];
#pragma unroll
                    for (int r = 0; r < 4; r++) {
                        int qg = Q0 + wave * 16 + quad * 4 + r;
                        float v = (cg <= qg) ? fmaf(cs[ni][r], scale, mk) : -10000.0f;
                        sv[ni][r] = v;
                        mt[r] = fmaxf(mt[r], v);
                    }
                }
            } else {
#pragma unroll
                for (int ni = 0; ni < 4; ni++) {
                    float mk = mb[c0 + ni * 16 + ln15];
#pragma unroll
                    for (int r = 0; r < 4; r++) {
                        float v = fmaf(cs[ni][r], scale, mk);
                        sv[ni][r] = v;
                        mt[r] = fmaxf(mt[r], v);
                    }
                }
            }
#pragma unroll
            for (int m = 1; m < 16; m <<= 1)
#pragma unroll
                for (int r = 0; r < 4; r++) mt[r] = fmaxf(mt[r], __shfl_xor(mt[r], m));

            // T13 defer-max
            bool grow = false;
#pragma unroll
            for (int r = 0; r < 4; r++) grow = grow || (mt[r] > m_r[r] + 8.0f);
            if (__any((int)grow)) {
#pragma unroll
                for (int r = 0; r < 4; r++) {
                    float mn = fmaxf(m_r[r], mt[r]);
                    float al = __expf(m_r[r] - mn);
                    m_r[r] = mn;
                    l_r[r] *= al;
#pragma unroll
                    for (int nj = 0; nj < 8; nj++) o[nj][r] *= al;
                }
            }

            // P = exp(s - m), row sums
            float lt[4] = {0.0f, 0.0f, 0.0f, 0.0f};
#pragma unroll
            for (int ni = 0; ni < 4; ni++)
#pragma unroll
                for (int r = 0; r < 4; r++) {
                    float p = __expf(sv[ni][r] - m_r[r]);
                    sv[ni][r] = p;
                    lt[r] += p;
                }
#pragma unroll
            for (int m = 1; m < 16; m <<= 1)
#pragma unroll
                for (int r = 0; r < 4; r++) lt[r] += __shfl_xor(lt[r], m);
#pragma unroll
            for (int r = 0; r < 4; r++) l_r[r] += lt[r];

            // P (C-layout) -> LDS -> A-layout (wave-private region)
            unsigned short* pw = &Pl[wave * 16 * 72];
#pragma unroll
            for (int ni = 0; ni < 4; ni++)
#pragma unroll
                for (int r = 0; r < 4; r++)
                    pw[(quad * 4 + r) * 72 + ni * 16 + ln15] = f2bf(sv[ni][r]);

            // O += P @ V, swizzled V reads
            __builtin_amdgcn_s_setprio(1);
#pragma unroll
            for (int ks2 = 0; ks2 < 2; ks2++) {
                bf16x8 pf = *(const bf16x8*)&Pl[(wave * 16 + ln15) * 72 + ks2 * 32 + quad * 8];
#pragma unroll
                for (int nj = 0; nj < 8; nj++) {
                    int dd = nj * 16 + ln15;
                    int sl = (ks2 * 4 + quad) ^ x7;
                    bf16x8 vf = *(const bf16x8*)&VtB[dd * 64 + sl * 8];
                    o[nj] = MFMA16(pf, vf, o[nj]);
                }
            }
            __builtin_amdgcn_s_setprio(0);
            __builtin_amdgcn_s_barrier();   // all reads of cur done -> reusable
            cur ^= 1;
        }

        float rl[4];
#pragma unroll
        for (int r = 0; r < 4; r++) rl[r] = 1.0f / l_r[r];
#pragma unroll
        for (int nj = 0; nj < 8; nj++)
#pragma unroll
            for (int r = 0; r < 4; r++) {
                int s = Q0 + wave * 16 + quad * 4 + r;
                size_t off = ((size_t)(b * 2048 + s)) * 2048 + h * 128 + nj * 16 + ln15;
                float val = o[nj][r] * rl[r];
                ctxo[off] = val;
                ctxb[off] = f2bf(val);
            }
    }
}

extern "C" void kernel_launch(void* const* d_in, const int* in_sizes, int n_in,
                              void* d_out, int out_size, void* d_ws, size_t ws_size,
                              hipStream_t stream) {
    const float* x      = (const float*)d_in[0];
    const float* mask   = (const float*)d_in[1];
    const float* qkvw   = (const float*)d_in[2];
    const float* qkvb   = (const float*)d_in[3];
    const float* ow     = (const float*)d_in[4];
    const float* norm_w = (const float*)d_in[5];
    const float* norm_b = (const float*)d_in[6];

    float* out      = (float*)d_out;             // [B,S,H]
    float* k_out    = out + 8388608;             // [B,Hd,S,dh]
    float* v_out    = out + 16777216;            // [B,Hd,S,dh]
    float* ctx_out  = out + 25165824;            // [B,S,H]
    float* norm_out = out + 33554432;            // [B,S,H]

    unsigned short* ws    = (unsigned short*)d_ws;
    unsigned short* xn    = ws;                        // 8,388,608  bf16 (LN out; later ctx bf16)
    unsigned short* qkvwT = ws + 8388608;              // 12,582,912 bf16 [6144][2048]
    unsigned short* owT   = ws + 8388608 + 12582912;   // 4,194,304  bf16 [2048][2048]
    unsigned short* qws   = owT + 4194304;             // 8,388,608  bf16 [B*S][H]
    unsigned short* vT    = qws + 8388608;             // 8,388,608  bf16 [B*Hd][dh][S]
    unsigned short* kbf   = vT + 8388608;              // 8,388,608  bf16 [B*Hd][S][dh]

    prep_kernel<<<8192, 256, 0, stream>>>(x, norm_w, norm_b, norm_out, xn,
                                          qkvw, qkvwT, ow, owT);
    gemm_qkv<<<dim3(384), 512, 0, stream>>>(xn, qkvwT, qkvb, k_out, v_out, qws, kbf);
    transpose_cvt<<<dim3(2, 32, 32), 256, 0, stream>>>(v_out, vT, 2048, 128);
    attn_kernel<<<dim3(16, 16, 2), 256, 0, stream>>>(qws, kbf, vT, mask, ctx_out, xn);
    gemm_out<<<dim3(512), 256, 0, stream>>>(xn, owT, out);
}